// Round 1
// baseline (1077.410 us; speedup 1.0000x reference)
//
#include <hip/hip_runtime.h>
#include <math.h>

// ---- problem dims ----
constexpr int cB = 8, cN = 2048, cI = 64, cH = 128, cO = 8, cK = 24;
constexpr int ROWS = cB * cN; // 16384

// ---- ws layout (floats) ----
constexpr size_t WS_SPATIAL = 0;                                  // 16384*128
constexpr size_t WS_SQ      = WS_SPATIAL + (size_t)ROWS * cH;     // 16384
constexpr size_t WS_GHS     = WS_SQ + ROWS;                       // 8*384
constexpr size_t WS_NSQ0    = WS_GHS + (size_t)cO * 3 * cH;       // 8
constexpr size_t WS_NEWOBJ  = WS_NSQ0 + cO;                       // 8*8*128
constexpr size_t WS_NSQ     = WS_NEWOBJ + (size_t)cB * cO * cH;   // 64
constexpr size_t WS_UPD     = WS_NSQ + (size_t)cB * cO;           // 8*24*128
constexpr size_t WS_S       = WS_UPD + (size_t)cB * cK * cH;      // 192

// ---- d_out layout (floats), return order: slots, attn, pred_time, density ----
constexpr size_t OUT_SLOTS = 0;                                   // 8*24*129
constexpr size_t OUT_ATTN  = (size_t)cB * cK * 129;               // 24768
constexpr size_t OUT_PT    = OUT_ATTN + (size_t)cB * cK * cN;     // 417984
constexpr size_t OUT_DEN   = OUT_PT + (size_t)cB * cN;            // 434368

typedef __attribute__((ext_vector_type(8))) short bf16x8;
typedef __attribute__((ext_vector_type(4))) float f32x4;

__device__ __forceinline__ float gelu_f(float v){
  return 0.5f * v * (1.f + erff(v * 0.70710678118654752440f));
}
__device__ __forceinline__ short f2bf(float f){
  unsigned u = __float_as_uint(f);
  u += 0x7fffu + ((u >> 16) & 1u);   // RNE
  return (short)(u >> 16);
}
__device__ __forceinline__ bf16x8 pack8(float4 a, float4 b){
  bf16x8 r;
  r[0]=f2bf(a.x); r[1]=f2bf(a.y); r[2]=f2bf(a.z); r[3]=f2bf(a.w);
  r[4]=f2bf(b.x); r[5]=f2bf(b.y); r[6]=f2bf(b.z); r[7]=f2bf(b.w);
  return r;
}

// ---------------- sq[b,n] = ||x||^2 ----------------
__global__ __launch_bounds__(256) void k_sq(const float* __restrict__ x, float* __restrict__ sq){
  int r = blockIdx.x * 256 + threadIdx.x;
  if (r >= ROWS) return;
  const float4* xp = (const float4*)(x + (size_t)r * cI);
  float s = 0.f;
  #pragma unroll
  for (int i = 0; i < 16; ++i){ float4 v = xp[i]; s += v.x*v.x + v.y*v.y + v.z*v.z + v.w*v.w; }
  sq[r] = s;
}

// ---------------- precompute gh = obj @ W_hh^T + b_hh (b-independent), and ||obj_o||^2 ----------------
__global__ __launch_bounds__(256) void k_prep(const float* __restrict__ objsp, const float* __restrict__ w_hh,
                                              const float* __restrict__ b_hh, float* __restrict__ ghs,
                                              float* __restrict__ nsq0){
  int id = blockIdx.x * 256 + threadIdx.x;
  if (id < cO * 3 * cH){
    int o = id / (3 * cH), j = id % (3 * cH);
    const float* wr = w_hh + (size_t)j * cH;
    const float* ob = objsp + (size_t)o * cH;
    float a0=0,a1=0,a2=0,a3=0;
    #pragma unroll
    for (int h = 0; h < cH; h += 4){
      a0 += wr[h]*ob[h]; a1 += wr[h+1]*ob[h+1]; a2 += wr[h+2]*ob[h+2]; a3 += wr[h+3]*ob[h+3];
    }
    ghs[id] = (a0+a1)+(a2+a3) + b_hh[j];
  } else if (id < cO * 3 * cH + cO){
    int o = id - cO * 3 * cH;
    const float* ob = objsp + (size_t)o * cH;
    float s = 0.f;
    for (int h = 0; h < cH; ++h) s += ob[h]*ob[h];
    nsq0[o] = s;
  }
}

// ---------------- pairwise distances (bf16 MFMA) + fused per-row top-6 -> density ----------------
// block: 16 rows of one b; 4 waves split the 2048 cols (512 each, 32 col-tiles of 16).
__global__ __launch_bounds__(256) void k_pairwise(const float* __restrict__ x, const float* __restrict__ sq,
                                                  float* __restrict__ den_out){
  __shared__ float cand[4][16][96];
  int b  = blockIdx.x >> 7;
  int rt = blockIdx.x & 127;
  int r0 = rt * 16;
  int lane = threadIdx.x & 63, w = threadIdx.x >> 6;
  const float* xb = x + (size_t)b * cN * cI;

  int arow = r0 + (lane & 15);
  int koff = (lane >> 4) * 8;
  const float4* ap = (const float4*)(xb + (size_t)arow * cI + koff);
  bf16x8 a0 = pack8(ap[0], ap[1]);   // k = koff..koff+7
  bf16x8 a1 = pack8(ap[8], ap[9]);   // k = 32+koff..

  float sqr[4];
  int rg0 = r0 + ((lane >> 4) << 2);
  #pragma unroll
  for (int j = 0; j < 4; ++j) sqr[j] = sq[b * cN + rg0 + j];

  float t[4][6];
  #pragma unroll
  for (int j = 0; j < 4; ++j){
    #pragma unroll
    for (int q = 0; q < 6; ++q) t[j][q] = 3e38f;
  }

  int cbase = w * 512;
  for (int ct = 0; ct < 32; ++ct){
    int col0 = cbase + ct * 16;
    int brow = col0 + (lane & 15);
    const float4* bp = (const float4*)(xb + (size_t)brow * cI + koff);
    bf16x8 b0 = pack8(bp[0], bp[1]);
    bf16x8 b1 = pack8(bp[8], bp[9]);
    f32x4 acc = {0.f, 0.f, 0.f, 0.f};
    acc = __builtin_amdgcn_mfma_f32_16x16x32_bf16(a0, b0, acc, 0, 0, 0);
    acc = __builtin_amdgcn_mfma_f32_16x16x32_bf16(a1, b1, acc, 0, 0, 0);
    float sqc = sq[b * cN + col0 + (lane & 15)];
    #pragma unroll
    for (int j = 0; j < 4; ++j){
      float d2 = sqr[j] + sqc - 2.f * acc[j];  // C layout: col=lane&15, row=(lane>>4)*4+j
      d2 = fmaxf(d2, 0.f);
      if (d2 < t[j][5]){
        if (d2 < t[j][4]){ t[j][5]=t[j][4];
          if (d2 < t[j][3]){ t[j][4]=t[j][3];
            if (d2 < t[j][2]){ t[j][3]=t[j][2];
              if (d2 < t[j][1]){ t[j][2]=t[j][1];
                if (d2 < t[j][0]){ t[j][1]=t[j][0]; t[j][0]=d2; } else t[j][1]=d2;
              } else t[j][2]=d2;
            } else t[j][3]=d2;
          } else t[j][4]=d2;
        } else t[j][5]=d2;
      }
    }
  }
  int rloc = (lane >> 4) << 2;
  #pragma unroll
  for (int j = 0; j < 4; ++j){
    #pragma unroll
    for (int q = 0; q < 6; ++q) cand[w][rloc + j][(lane & 15) * 6 + q] = t[j][q];
  }
  __syncthreads();
  int tt = threadIdx.x;
  if (tt < 16){
    float m0=3e38f,m1=3e38f,m2=3e38f,m3=3e38f,m4=3e38f,m5=3e38f;
    for (int ww = 0; ww < 4; ++ww){
      const float* c = cand[ww][tt];
      for (int q = 0; q < 96; ++q){
        float v = c[q];
        if (v < m5){
          if (v<m4){ m5=m4; if (v<m3){ m4=m3; if (v<m2){ m3=m2; if (v<m1){ m2=m1; if (v<m0){ m1=m0; m0=v; } else m1=v; } else m2=v; } else m3=v; } else m4=v; } else m5=v;
        }
      }
    }
    // drop smallest (self ~0), mean of next 5 distances
    float md = (sqrtf(m1)+sqrtf(m2)+sqrtf(m3)+sqrtf(m4)+sqrtf(m5)) * 0.2f;
    den_out[b * cN + r0 + tt] = tanhf(md);
  }
}

// ---------------- encoder: h=gelu(ln(x@W1^T+b1)); spatial=ln(h@W2^T+b2) ----------------
// 1 wave/block; pair (t, t^32) shares one row, each computes 64 of 128 outputs.
__global__ __launch_bounds__(64) void k_encoder(const float* __restrict__ x,
    const float* __restrict__ w1, const float* __restrict__ b1v, const float* __restrict__ g1, const float* __restrict__ bb1,
    const float* __restrict__ w2, const float* __restrict__ b2v, const float* __restrict__ g2, const float* __restrict__ bb2,
    float* __restrict__ spatial){
  __shared__ float hbuf[32][130];
  int t = threadIdx.x;
  int rl = t & 31, hf = t >> 5;
  int row = blockIdx.x * 32 + rl;
  float xv[64];
  const float4* xp = (const float4*)(x + (size_t)row * cI);
  #pragma unroll
  for (int i = 0; i < 16; ++i){ float4 v = xp[i]; xv[4*i]=v.x; xv[4*i+1]=v.y; xv[4*i+2]=v.z; xv[4*i+3]=v.w; }

  float sm = 0.f, s2 = 0.f;
  #pragma unroll 2
  for (int ff = 0; ff < 64; ++ff){
    int f = hf * 64 + ff;
    const float* wr = w1 + (size_t)f * cI;   // uniform address -> scalar loads
    float a0=0,a1=0,a2=0,a3=0;
    #pragma unroll
    for (int d = 0; d < cI; d += 4){
      a0 += wr[d]*xv[d]; a1 += wr[d+1]*xv[d+1]; a2 += wr[d+2]*xv[d+2]; a3 += wr[d+3]*xv[d+3];
    }
    float a = (a0+a1)+(a2+a3) + b1v[f];
    hbuf[rl][f] = a;
    sm += a; s2 += a*a;
  }
  sm += __shfl_xor(sm, 32); s2 += __shfl_xor(s2, 32);
  float mean = sm * (1.f/128.f);
  float rstd = rsqrtf(s2 * (1.f/128.f) - mean*mean + 1e-5f);
  __syncthreads();
  float hv[128];
  #pragma unroll
  for (int d = 0; d < cH; ++d){
    float a = (hbuf[rl][d] - mean) * rstd * g1[d] + bb1[d];
    hv[d] = gelu_f(a);
  }
  __syncthreads();
  float sm2 = 0.f, q2 = 0.f;
  #pragma unroll 2
  for (int ff = 0; ff < 64; ++ff){
    int f = hf * 64 + ff;
    const float* wr = w2 + (size_t)f * cH;
    float a0=0,a1=0,a2=0,a3=0;
    #pragma unroll
    for (int d = 0; d < cH; d += 4){
      a0 += wr[d]*hv[d]; a1 += wr[d+1]*hv[d+1]; a2 += wr[d+2]*hv[d+2]; a3 += wr[d+3]*hv[d+3];
    }
    float a = (a0+a1)+(a2+a3) + b2v[f];
    hbuf[rl][f] = a;
    sm2 += a; q2 += a*a;
  }
  sm2 += __shfl_xor(sm2, 32); q2 += __shfl_xor(q2, 32);
  float mean2 = sm2 * (1.f/128.f);
  float rstd2 = rsqrtf(q2 * (1.f/128.f) - mean2*mean2 + 1e-5f);
  __syncthreads();
  float* srow = spatial + (size_t)row * cH;
  #pragma unroll
  for (int ff = 0; ff < 64; ++ff){
    int f = hf * 64 + ff;
    srow[f] = (hbuf[rl][f] - mean2) * rstd2 * g2[f] + bb2[f];
  }
}

// ---------------- spatial head: s=gelu(ln([spatial,den]@W^T+b)); pred_time ----------------
__global__ __launch_bounds__(64) void k_head(const float* __restrict__ spatial, const float* __restrict__ den_in,
    const float* __restrict__ w1, const float* __restrict__ b1v, const float* __restrict__ gv, const float* __restrict__ bbv,
    const float* __restrict__ w2v, const float* __restrict__ b2v, float* __restrict__ pt_out){
  __shared__ float hbuf[32][130];
  int t = threadIdx.x, rl = t & 31, hf = t >> 5;
  int row = blockIdx.x * 32 + rl;
  float sv[128];
  const float4* sp4 = (const float4*)(spatial + (size_t)row * cH);
  #pragma unroll
  for (int i = 0; i < 32; ++i){ float4 v = sp4[i]; sv[4*i]=v.x; sv[4*i+1]=v.y; sv[4*i+2]=v.z; sv[4*i+3]=v.w; }
  float den = den_in[row];
  float sm = 0.f, s2 = 0.f;
  #pragma unroll 2
  for (int ff = 0; ff < 64; ++ff){
    int f = hf * 64 + ff;
    const float* wr = w1 + (size_t)f * 129;
    float a0=0,a1=0,a2=0,a3=0;
    #pragma unroll
    for (int d = 0; d < cH; d += 4){
      a0 += wr[d]*sv[d]; a1 += wr[d+1]*sv[d+1]; a2 += wr[d+2]*sv[d+2]; a3 += wr[d+3]*sv[d+3];
    }
    float a = (a0+a1)+(a2+a3) + wr[128]*den + b1v[f];
    hbuf[rl][f] = a;
    sm += a; s2 += a*a;
  }
  sm += __shfl_xor(sm, 32); s2 += __shfl_xor(s2, 32);
  float mean = sm * (1.f/128.f);
  float rstd = rsqrtf(s2 * (1.f/128.f) - mean*mean + 1e-5f);
  __syncthreads();
  float p0=0,p1=0,p2=0,p3=0;
  #pragma unroll
  for (int d = 0; d < cH; d += 4){
    float e0 = gelu_f((hbuf[rl][d]   - mean)*rstd*gv[d]   + bbv[d]);
    float e1 = gelu_f((hbuf[rl][d+1] - mean)*rstd*gv[d+1] + bbv[d+1]);
    float e2 = gelu_f((hbuf[rl][d+2] - mean)*rstd*gv[d+2] + bbv[d+2]);
    float e3 = gelu_f((hbuf[rl][d+3] - mean)*rstd*gv[d+3] + bbv[d+3]);
    p0 += e0*w2v[d]; p1 += e1*w2v[d+1]; p2 += e2*w2v[d+2]; p3 += e3*w2v[d+3];
  }
  if (hf == 0){
    float ps = (p0+p1)+(p2+p3) + b2v[0];
    float spl = fmaxf(ps, 0.f) + log1pf(expf(-fabsf(ps)));  // stable softplus
    pt_out[row] = 5.f - 1.5f*den + 0.5f*spl;
  }
}

// ---------------- attention logits + softmax over K (dr2 via expansion; only 8 o-dots) ----------------
__global__ __launch_bounds__(128) void k_attn(const float* __restrict__ spatial, const float* __restrict__ pt_in,
    const float* __restrict__ den_in, const float* __restrict__ objp, int ob_stride,
    const float* __restrict__ nsqp, int nq_stride,
    const float* __restrict__ lt, const float* __restrict__ bh, const float* __restrict__ hs,
    float* __restrict__ attn_out){
  int id = blockIdx.x * 128 + threadIdx.x;
  int b = id >> 11, n = id & 2047;
  float sv[128];
  const float4* sp4 = (const float4*)(spatial + (size_t)id * cH);
  #pragma unroll
  for (int i = 0; i < 32; ++i){ float4 v = sp4[i]; sv[4*i]=v.x; sv[4*i+1]=v.y; sv[4*i+2]=v.z; sv[4*i+3]=v.w; }
  float q0=0,q1=0,q2=0,q3=0;
  #pragma unroll
  for (int d = 0; d < cH; d += 4){ q0+=sv[d]*sv[d]; q1+=sv[d+1]*sv[d+1]; q2+=sv[d+2]*sv[d+2]; q3+=sv[d+3]*sv[d+3]; }
  float spn2 = (q0+q1)+(q2+q3);

  const float* ob = objp + (size_t)b * ob_stride;
  float acc[8];
  #pragma unroll
  for (int o = 0; o < 8; ++o){
    const float* orow = ob + (size_t)o * cH;
    float a0=0,a1=0,a2=0,a3=0;
    #pragma unroll
    for (int d = 0; d < cH; d += 4){
      a0 += orow[d]*sv[d]; a1 += orow[d+1]*sv[d+1]; a2 += orow[d+2]*sv[d+2]; a3 += orow[d+3]*sv[d+3];
    }
    acc[o] = (a0+a1)+(a2+a3);
  }
  const float* nq = nsqp + (size_t)b * nq_stride;
  float nsqv_[8];
  #pragma unroll
  for (int o = 0; o < 8; ++o) nsqv_[o] = nq[o];

  float pt = pt_in[id], den = den_in[id];
  float hsv = hs[0];
  float lts[3] = { lt[0], lt[1], lt[2] };
  float bhs[3] = { bh[0], bh[1], bh[2] };

  float logits[24];
  #pragma unroll
  for (int k = 0; k < 24; ++k){
    const int o = k / 3, l = k % 3;
    float dtv = pt - lts[l];
    float dr2 = fmaxf(spn2 + nsqv_[o] - 2.f * acc[o], 0.f);
    float ls  = dtv*dtv - dr2;
    float adL = sqrtf(fabsf(ls) + 1e-6f);           // |d_L|
    float r   = sqrtf(dr2);
    float adt = fabsf(dtv);
    float hz  = fminf(fmaxf(bhs[l] + hsv * (den - 0.5f), 0.1f), 1.0f);
    float cone = hz - r / (adt + 1e-6f) - 10.f * fmaxf(-dtv, 0.f) - 5.f * fmaxf(r - adt, 0.f);
    logits[k] = (-adL + 0.5f * tanhf(cone)) * 10.f; // /TAU
  }
  float mx = -3e38f;
  #pragma unroll
  for (int k = 0; k < 24; ++k) mx = fmaxf(mx, logits[k]);
  float es[24]; float ssum = 0.f;
  #pragma unroll
  for (int k = 0; k < 24; ++k){ es[k] = expf(logits[k] - mx); ssum += es[k]; }
  float inv = 1.f / ssum;
  float* ao = attn_out + (size_t)b * cK * cN + n;
  #pragma unroll
  for (int k = 0; k < 24; ++k) ao[(size_t)k * cN] = es[k] * inv;
}

// ---------------- upd_raw[b,k,h] += sum_n attn*spatial ; S[b,k] += sum_n attn ----------------
__global__ __launch_bounds__(256) void k_upd(const float* __restrict__ spatial, const float* __restrict__ attn,
                                             float* __restrict__ upd_raw, float* __restrict__ Ssum){
  int blk = blockIdx.x;            // 8*16
  int b = blk >> 4, chunk = blk & 15;
  int n0 = chunk * 128;
  int t = threadIdx.x;
  int h = t & 127, g = t >> 7;     // g selects k-group of 12
  float acc[12], sac[12];
  #pragma unroll
  for (int kk = 0; kk < 12; ++kk){ acc[kk] = 0.f; sac[kk] = 0.f; }
  const float* ab = attn + (size_t)b * cK * cN;
  for (int ni = 0; ni < 128; ++ni){
    int n = n0 + ni;
    float spv = spatial[((size_t)b * cN + n) * cH + h];
    #pragma unroll
    for (int kk = 0; kk < 12; ++kk){
      float a = ab[(size_t)(g * 12 + kk) * cN + n];
      acc[kk] += a * spv;
      sac[kk] += a;
    }
  }
  #pragma unroll
  for (int kk = 0; kk < 12; ++kk)
    atomicAdd(&upd_raw[((size_t)b * cK + g * 12 + kk) * cH + h], acc[kk]);
  if (h == 0){
    #pragma unroll
    for (int kk = 0; kk < 12; ++kk) atomicAdd(&Ssum[b * cK + g * 12 + kk], sac[kk]);
  }
}

// ---------------- GRU + LN + MLP residual; writes newobj/nsq (+ slots on final iter) ----------------
__global__ __launch_bounds__(128) void k_gru(const float* __restrict__ upd_raw, const float* __restrict__ Ssum,
    const float* __restrict__ ghs, const float* __restrict__ objsp,
    const float* __restrict__ w_ih, const float* __restrict__ b_ih,
    const float* __restrict__ mw1, const float* __restrict__ mb1,
    const float* __restrict__ mw2, const float* __restrict__ mb2,
    const float* __restrict__ ng_, const float* __restrict__ nb_,
    const float* __restrict__ lt,
    float* __restrict__ newobj, float* __restrict__ nsq,
    float* __restrict__ slots_out, int writeSlots){
  __shared__ float ubuf[cH], lbuf[cH], gbuf[cH], red[8];
  int bo = blockIdx.x; int b = bo >> 3, o = bo & 7;
  int t = threadIdx.x;
  int lane = t & 63, wid = t >> 6;

  float u = 0.f;
  #pragma unroll
  for (int l = 0; l < 3; ++l){
    int k = o * 3 + l;
    float s = Ssum[b * cK + k] + 1e-8f;
    u += upd_raw[((size_t)b * cK + k) * cH + t] / s;
  }
  ubuf[t] = u;
  __syncthreads();

  float gi[3];
  #pragma unroll
  for (int j3 = 0; j3 < 3; ++j3){
    const float* wr = w_ih + ((size_t)j3 * cH + t) * cH;
    float a0=0,a1=0,a2=0,a3=0;
    #pragma unroll
    for (int d = 0; d < cH; d += 4){
      a0 += wr[d]*ubuf[d]; a1 += wr[d+1]*ubuf[d+1]; a2 += wr[d+2]*ubuf[d+2]; a3 += wr[d+3]*ubuf[d+3];
    }
    gi[j3] = (a0+a1)+(a2+a3) + b_ih[j3 * cH + t];
  }
  const float* gh = ghs + (size_t)o * 3 * cH;
  float ghr = gh[t], ghz = gh[cH + t], ghn = gh[2 * cH + t];
  float oldv = objsp[(size_t)o * cH + t];
  float rg = 1.f / (1.f + expf(-(gi[0] + ghr)));
  float zg = 1.f / (1.f + expf(-(gi[1] + ghz)));
  float ngv = tanhf(gi[2] + rg * ghn);
  float nv = (1.f - zg) * ngv + zg * oldv;

  // LN across the 128 threads
  float s1 = nv, s2 = nv * nv;
  #pragma unroll
  for (int m = 1; m < 64; m <<= 1){ s1 += __shfl_xor(s1, m); s2 += __shfl_xor(s2, m); }
  if (lane == 0){ red[wid] = s1; red[4 + wid] = s2; }
  __syncthreads();
  float mean = (red[0] + red[1]) * (1.f/128.f);
  float var  = (red[4] + red[5]) * (1.f/128.f) - mean * mean;
  float ln = (nv - mean) * rsqrtf(var + 1e-5f) * ng_[t] + nb_[t];
  lbuf[t] = ln;
  __syncthreads();

  const float* w1r = mw1 + (size_t)t * cH;
  {
    float a0=0,a1=0,a2=0,a3=0;
    #pragma unroll
    for (int d = 0; d < cH; d += 4){
      a0 += w1r[d]*lbuf[d]; a1 += w1r[d+1]*lbuf[d+1]; a2 += w1r[d+2]*lbuf[d+2]; a3 += w1r[d+3]*lbuf[d+3];
    }
    gbuf[t] = gelu_f((a0+a1)+(a2+a3) + mb1[t]);
  }
  __syncthreads();
  const float* w2r = mw2 + (size_t)t * cH;
  float m2v;
  {
    float a0=0,a1=0,a2=0,a3=0;
    #pragma unroll
    for (int d = 0; d < cH; d += 4){
      a0 += w2r[d]*gbuf[d]; a1 += w2r[d+1]*gbuf[d+1]; a2 += w2r[d+2]*gbuf[d+2]; a3 += w2r[d+3]*gbuf[d+3];
    }
    m2v = (a0+a1)+(a2+a3) + mb2[t];
  }
  float outv = nv + 0.2f * m2v;
  newobj[((size_t)b * cO + o) * cH + t] = outv;

  float qv = outv * outv;
  #pragma unroll
  for (int m = 1; m < 64; m <<= 1) qv += __shfl_xor(qv, m);
  __syncthreads();
  if (lane == 0) red[wid] = qv;
  __syncthreads();
  if (t == 0) nsq[b * cO + o] = red[0] + red[1];

  if (writeSlots){
    #pragma unroll
    for (int l = 0; l < 3; ++l){
      size_t base = ((size_t)b * cK + o * 3 + l) * 129;
      slots_out[base + 1 + t] = outv;
      if (t == 0) slots_out[base] = lt[l];
    }
  }
}

extern "C" void kernel_launch(void* const* d_in, const int* in_sizes, int n_in,
                              void* d_out, int out_size, void* d_ws, size_t ws_size,
                              hipStream_t stream){
  const float* x       = (const float*)d_in[0];
  const float* enc_w1  = (const float*)d_in[1];
  const float* enc_b1  = (const float*)d_in[2];
  const float* enc_g1  = (const float*)d_in[3];
  const float* enc_bb1 = (const float*)d_in[4];
  const float* enc_w2  = (const float*)d_in[5];
  const float* enc_b2  = (const float*)d_in[6];
  const float* enc_g2  = (const float*)d_in[7];
  const float* enc_bb2 = (const float*)d_in[8];
  const float* sp_w1   = (const float*)d_in[9];
  const float* sp_b1   = (const float*)d_in[10];
  const float* sp_g    = (const float*)d_in[11];
  const float* sp_bb   = (const float*)d_in[12];
  const float* sp_w2   = (const float*)d_in[13];
  const float* sp_b2   = (const float*)d_in[14];
  const float* objsp   = (const float*)d_in[15];
  const float* hscale  = (const float*)d_in[16];
  const float* ltimes  = (const float*)d_in[17];
  const float* bhor    = (const float*)d_in[18];
  const float* gw_ih   = (const float*)d_in[19];
  const float* gw_hh   = (const float*)d_in[20];
  const float* gb_ih   = (const float*)d_in[21];
  const float* gb_hh   = (const float*)d_in[22];
  const float* mw1     = (const float*)d_in[23];
  const float* mb1     = (const float*)d_in[24];
  const float* mw2     = (const float*)d_in[25];
  const float* mb2     = (const float*)d_in[26];
  const float* normg   = (const float*)d_in[27];
  const float* normb   = (const float*)d_in[28];
  (void)in_sizes; (void)n_in; (void)out_size; (void)ws_size;

  float* out = (float*)d_out;
  float* ws  = (float*)d_ws;

  float* spatial = ws + WS_SPATIAL;
  float* sq      = ws + WS_SQ;
  float* ghs     = ws + WS_GHS;
  float* nsq0    = ws + WS_NSQ0;
  float* newobj  = ws + WS_NEWOBJ;
  float* nsqv    = ws + WS_NSQ;
  float* updr    = ws + WS_UPD;
  float* Ss      = ws + WS_S;

  k_sq<<<dim3(ROWS / 256), dim3(256), 0, stream>>>(x, sq);
  k_prep<<<dim3(13), dim3(256), 0, stream>>>(objsp, gw_hh, gb_hh, ghs, nsq0);
  k_encoder<<<dim3(ROWS / 32), dim3(64), 0, stream>>>(x, enc_w1, enc_b1, enc_g1, enc_bb1,
                                                      enc_w2, enc_b2, enc_g2, enc_bb2, spatial);
  k_pairwise<<<dim3(cB * (cN / 16)), dim3(256), 0, stream>>>(x, sq, out + OUT_DEN);
  k_head<<<dim3(ROWS / 32), dim3(64), 0, stream>>>(spatial, out + OUT_DEN, sp_w1, sp_b1, sp_g, sp_bb,
                                                   sp_w2, sp_b2, out + OUT_PT);

  for (int it = 0; it < 3; ++it){
    hipMemsetAsync((void*)updr, 0, (size_t)(cB * cK * cH + cB * cK) * sizeof(float), stream);
    const float* objp = (it == 0) ? objsp : newobj;
    int obst = (it == 0) ? 0 : cO * cH;
    const float* nqp = (it == 0) ? nsq0 : nsqv;
    int nqst = (it == 0) ? 0 : cO;
    k_attn<<<dim3(ROWS / 128), dim3(128), 0, stream>>>(spatial, out + OUT_PT, out + OUT_DEN,
                                                       objp, obst, nqp, nqst,
                                                       ltimes, bhor, hscale, out + OUT_ATTN);
    k_upd<<<dim3(cB * 16), dim3(256), 0, stream>>>(spatial, out + OUT_ATTN, updr, Ss);
    k_gru<<<dim3(cB * cO), dim3(128), 0, stream>>>(updr, Ss, ghs, objsp, gw_ih, gb_ih,
                                                   mw1, mb1, mw2, mb2, normg, normb, ltimes,
                                                   newobj, nsqv, out + OUT_SLOTS, (it == 2) ? 1 : 0);
  }
}

// Round 2
// 814.227 us; speedup vs baseline: 1.3232x; 1.3232x over previous
//
#include <hip/hip_runtime.h>
#include <math.h>

// ---- problem dims ----
constexpr int cB = 8, cN = 2048, cI = 64, cH = 128, cO = 8, cK = 24;
constexpr int ROWS = cB * cN; // 16384

// ---- ws layout (floats) ----
constexpr size_t WS_SPATIAL = 0;                                  // 16384*128
constexpr size_t WS_SQ      = WS_SPATIAL + (size_t)ROWS * cH;     // 16384
constexpr size_t WS_GHS     = WS_SQ + ROWS;                       // 8*384
constexpr size_t WS_NSQ0    = WS_GHS + (size_t)cO * 3 * cH;       // 8
constexpr size_t WS_NEWOBJ  = WS_NSQ0 + cO;                       // 8*8*128
constexpr size_t WS_NSQ     = WS_NEWOBJ + (size_t)cB * cO * cH;   // 64
constexpr size_t WS_SPW1P   = WS_NSQ + (size_t)cB * cO;           // 128*132 padded sp_w1
constexpr size_t WS_UPD3    = WS_SPW1P + (size_t)cH * 132;        // 3*8*24*128
constexpr size_t WS_S3      = WS_UPD3 + (size_t)3 * cB * cK * cH; // 3*8*24 (contiguous after UPD3)

// ---- d_out layout (floats), return order: slots, attn, pred_time, density ----
constexpr size_t OUT_SLOTS = 0;                                   // 8*24*129
constexpr size_t OUT_ATTN  = (size_t)cB * cK * 129;
constexpr size_t OUT_PT    = OUT_ATTN + (size_t)cB * cK * cN;
constexpr size_t OUT_DEN   = OUT_PT + (size_t)cB * cN;

typedef __attribute__((ext_vector_type(8))) short bf16x8;
typedef __attribute__((ext_vector_type(4))) float f32x4;

__device__ __forceinline__ float gelu_f(float v){
  return 0.5f * v * (1.f + erff(v * 0.70710678118654752440f));
}
__device__ __forceinline__ short f2bf(float f){
  unsigned u = __float_as_uint(f);
  u += 0x7fffu + ((u >> 16) & 1u);   // RNE
  return (short)(u >> 16);
}
__device__ __forceinline__ bf16x8 pack8(float4 a, float4 b){
  bf16x8 r;
  r[0]=f2bf(a.x); r[1]=f2bf(a.y); r[2]=f2bf(a.z); r[3]=f2bf(a.w);
  r[4]=f2bf(b.x); r[5]=f2bf(b.y); r[6]=f2bf(b.z); r[7]=f2bf(b.w);
  return r;
}
__device__ __forceinline__ void red8(float& a){   // sum over 8-lane group (masks 1,2,4)
  a += __shfl_xor(a, 1); a += __shfl_xor(a, 2); a += __shfl_xor(a, 4);
}

// ---------------- sq[b,n] = ||x||^2 ----------------
__global__ __launch_bounds__(256) void k_sq(const float* __restrict__ x, float* __restrict__ sq){
  int r = blockIdx.x * 256 + threadIdx.x;
  if (r >= ROWS) return;
  const float4* xp = (const float4*)(x + (size_t)r * cI);
  float s = 0.f;
  #pragma unroll
  for (int i = 0; i < 16; ++i){ float4 v = xp[i]; s += v.x*v.x + v.y*v.y + v.z*v.z + v.w*v.w; }
  sq[r] = s;
}

// ---------------- prep: ghs (b-independent GRU gh), ||obj||^2, padded sp_w1 ----------------
__global__ __launch_bounds__(256) void k_prep(const float* __restrict__ objsp, const float* __restrict__ w_hh,
                                              const float* __restrict__ b_hh, const float* __restrict__ spw1,
                                              float* __restrict__ ghs, float* __restrict__ nsq0,
                                              float* __restrict__ spw1p){
  int id = blockIdx.x * 256 + threadIdx.x;
  if (id < cO * 3 * cH){
    int o = id / (3 * cH), j = id % (3 * cH);
    const float* wr = w_hh + (size_t)j * cH;
    const float* ob = objsp + (size_t)o * cH;
    float a0=0,a1=0,a2=0,a3=0;
    #pragma unroll
    for (int h = 0; h < cH; h += 4){
      a0 += wr[h]*ob[h]; a1 += wr[h+1]*ob[h+1]; a2 += wr[h+2]*ob[h+2]; a3 += wr[h+3]*ob[h+3];
    }
    ghs[id] = (a0+a1)+(a2+a3) + b_hh[j];
  } else if (id < cO * 3 * cH + cO){
    int o = id - cO * 3 * cH;
    const float* ob = objsp + (size_t)o * cH;
    float s = 0.f;
    for (int h = 0; h < cH; ++h) s += ob[h]*ob[h];
    nsq0[o] = s;
  } else {
    int idx = id - (cO * 3 * cH + cO);
    if (idx < cH * 129){
      int f = idx / 129, d = idx % 129;
      spw1p[(size_t)f * 132 + d] = spw1[idx];
    }
  }
}

// ---------------- pairwise distances (bf16 MFMA) + fused per-row top-6 -> density ----------------
__global__ __launch_bounds__(256) void k_pairwise(const float* __restrict__ x, const float* __restrict__ sq,
                                                  float* __restrict__ den_out){
  __shared__ float cand[4][16][96];
  int b  = blockIdx.x >> 7;
  int rt = blockIdx.x & 127;
  int r0 = rt * 16;
  int lane = threadIdx.x & 63, w = threadIdx.x >> 6;
  const float* xb = x + (size_t)b * cN * cI;

  int arow = r0 + (lane & 15);
  int koff = (lane >> 4) * 8;
  const float4* ap = (const float4*)(xb + (size_t)arow * cI + koff);
  bf16x8 a0 = pack8(ap[0], ap[1]);
  bf16x8 a1 = pack8(ap[8], ap[9]);

  float sqr[4];
  int rg0 = r0 + ((lane >> 4) << 2);
  #pragma unroll
  for (int j = 0; j < 4; ++j) sqr[j] = sq[b * cN + rg0 + j];

  float t[4][6];
  #pragma unroll
  for (int j = 0; j < 4; ++j){
    #pragma unroll
    for (int q = 0; q < 6; ++q) t[j][q] = 3e38f;
  }

  int cbase = w * 512;
  for (int ct = 0; ct < 32; ++ct){
    int col0 = cbase + ct * 16;
    int brow = col0 + (lane & 15);
    const float4* bp = (const float4*)(xb + (size_t)brow * cI + koff);
    bf16x8 b0 = pack8(bp[0], bp[1]);
    bf16x8 b1 = pack8(bp[8], bp[9]);
    f32x4 acc = {0.f, 0.f, 0.f, 0.f};
    acc = __builtin_amdgcn_mfma_f32_16x16x32_bf16(a0, b0, acc, 0, 0, 0);
    acc = __builtin_amdgcn_mfma_f32_16x16x32_bf16(a1, b1, acc, 0, 0, 0);
    float sqc = sq[b * cN + col0 + (lane & 15)];
    #pragma unroll
    for (int j = 0; j < 4; ++j){
      float d2 = sqr[j] + sqc - 2.f * acc[j];
      d2 = fmaxf(d2, 0.f);
      if (d2 < t[j][5]){
        if (d2 < t[j][4]){ t[j][5]=t[j][4];
          if (d2 < t[j][3]){ t[j][4]=t[j][3];
            if (d2 < t[j][2]){ t[j][3]=t[j][2];
              if (d2 < t[j][1]){ t[j][2]=t[j][1];
                if (d2 < t[j][0]){ t[j][1]=t[j][0]; t[j][0]=d2; } else t[j][1]=d2;
              } else t[j][2]=d2;
            } else t[j][3]=d2;
          } else t[j][4]=d2;
        } else t[j][5]=d2;
      }
    }
  }
  int rloc = (lane >> 4) << 2;
  #pragma unroll
  for (int j = 0; j < 4; ++j){
    #pragma unroll
    for (int q = 0; q < 6; ++q) cand[w][rloc + j][(lane & 15) * 6 + q] = t[j][q];
  }
  __syncthreads();
  int tt = threadIdx.x;
  if (tt < 16){
    float m0=3e38f,m1=3e38f,m2=3e38f,m3=3e38f,m4=3e38f,m5=3e38f;
    for (int ww = 0; ww < 4; ++ww){
      const float* c = cand[ww][tt];
      for (int q = 0; q < 96; ++q){
        float v = c[q];
        if (v < m5){
          if (v<m4){ m5=m4; if (v<m3){ m4=m3; if (v<m2){ m3=m2; if (v<m1){ m2=m1; if (v<m0){ m1=m0; m0=v; } else m1=v; } else m2=v; } else m3=v; } else m4=v; } else m5=v;
        }
      }
    }
    float md = (sqrtf(m1)+sqrtf(m2)+sqrtf(m3)+sqrtf(m4)+sqrtf(m5)) * 0.2f;
    den_out[b * cN + r0 + tt] = tanhf(md);
  }
}

// ---------------- fused encoder + spatial head ----------------
// 256 threads = 4 waves; 8 rows/wave, 8 threads/row (chunk = lane&7, 16 outputs each).
__global__ __launch_bounds__(256, 2) void k_enc_head(const float* __restrict__ x, const float* __restrict__ den_in,
    const float* __restrict__ w1, const float* __restrict__ b1v, const float* __restrict__ g1, const float* __restrict__ bb1,
    const float* __restrict__ w2, const float* __restrict__ b2v, const float* __restrict__ g2, const float* __restrict__ bb2,
    const float* __restrict__ hw1p, const float* __restrict__ hb1, const float* __restrict__ hg, const float* __restrict__ hbb,
    const float* __restrict__ hw2, const float* __restrict__ hb2,
    float* __restrict__ spatial, float* __restrict__ pt_out){
  __shared__ __align__(16) float hbuf[32][132];
  int t = threadIdx.x;
  int lane = t & 63, wid = t >> 6;
  int chunk = lane & 7, rsub = lane >> 3;
  int rloc = wid * 8 + rsub;
  int row = blockIdx.x * 32 + rloc;
  const int f0 = chunk * 16;

  // ---- layer 1: x(64) -> 16 outputs ----
  float4 xr[16];
  const float4* xp = (const float4*)(x + (size_t)row * cI);
  #pragma unroll
  for (int i = 0; i < 16; ++i) xr[i] = xp[i];

  float o1[16]; float sm = 0.f, s2 = 0.f;
  #pragma unroll
  for (int ff = 0; ff < 16; ++ff){
    const float4* wr = (const float4*)(w1 + (size_t)(f0 + ff) * cI);
    float a0=0,a1=0,a2=0,a3=0;
    #pragma unroll
    for (int i = 0; i < 16; ++i){ float4 w4 = wr[i];
      a0 += w4.x*xr[i].x; a1 += w4.y*xr[i].y; a2 += w4.z*xr[i].z; a3 += w4.w*xr[i].w; }
    float a = (a0+a1)+(a2+a3) + b1v[f0+ff];
    o1[ff] = a; sm += a; s2 += a*a;
  }
  red8(sm); red8(s2);
  float mean = sm * (1.f/128.f);
  float rstd = rsqrtf(s2 * (1.f/128.f) - mean*mean + 1e-5f);
  #pragma unroll
  for (int ff = 0; ff < 16; ++ff)
    hbuf[rloc][f0+ff] = gelu_f((o1[ff]-mean)*rstd*g1[f0+ff] + bb1[f0+ff]);
  __syncthreads();

  // ---- layer 2: h(128) -> 16 outputs ----
  float4 hr[32];
  const float4* hp = (const float4*)hbuf[rloc];
  #pragma unroll
  for (int i = 0; i < 32; ++i) hr[i] = hp[i];
  float o2[16]; sm = 0.f; s2 = 0.f;
  #pragma unroll
  for (int ff = 0; ff < 16; ++ff){
    const float4* wr = (const float4*)(w2 + (size_t)(f0 + ff) * cH);
    float a0=0,a1=0,a2=0,a3=0;
    #pragma unroll
    for (int i = 0; i < 32; ++i){ float4 w4 = wr[i];
      a0 += w4.x*hr[i].x; a1 += w4.y*hr[i].y; a2 += w4.z*hr[i].z; a3 += w4.w*hr[i].w; }
    float a = (a0+a1)+(a2+a3) + b2v[f0+ff];
    o2[ff] = a; sm += a; s2 += a*a;
  }
  red8(sm); red8(s2);
  float mean2 = sm * (1.f/128.f);
  float rstd2 = rsqrtf(s2 * (1.f/128.f) - mean2*mean2 + 1e-5f);
  float sv16[16];
  #pragma unroll
  for (int ff = 0; ff < 16; ++ff)
    sv16[ff] = (o2[ff]-mean2)*rstd2*g2[f0+ff] + bb2[f0+ff];
  float* srow = spatial + (size_t)row * cH + f0;
  #pragma unroll
  for (int ff = 0; ff < 16; ff += 4){
    float4 v = { sv16[ff], sv16[ff+1], sv16[ff+2], sv16[ff+3] };
    *(float4*)(srow + ff) = v;
  }
  __syncthreads();  // hbuf reads (hr) done by all waves before overwrite
  #pragma unroll
  for (int ff = 0; ff < 16; ++ff) hbuf[rloc][f0+ff] = sv16[ff];
  __syncthreads();

  // ---- head layer 1: [spatial(128), den] -> 16 outputs ----
  #pragma unroll
  for (int i = 0; i < 32; ++i) hr[i] = hp[i];
  float den = den_in[row];
  float o3[16]; sm = 0.f; s2 = 0.f;
  #pragma unroll
  for (int ff = 0; ff < 16; ++ff){
    const float4* wr = (const float4*)(hw1p + (size_t)(f0 + ff) * 132);
    float a0=0,a1=0,a2=0,a3=0;
    #pragma unroll
    for (int i = 0; i < 32; ++i){ float4 w4 = wr[i];
      a0 += w4.x*hr[i].x; a1 += w4.y*hr[i].y; a2 += w4.z*hr[i].z; a3 += w4.w*hr[i].w; }
    float a = (a0+a1)+(a2+a3) + hw1p[(size_t)(f0+ff) * 132 + 128] * den + hb1[f0+ff];
    o3[ff] = a; sm += a; s2 += a*a;
  }
  red8(sm); red8(s2);
  float mean3 = sm * (1.f/128.f);
  float rstd3 = rsqrtf(s2 * (1.f/128.f) - mean3*mean3 + 1e-5f);
  float part = 0.f;
  #pragma unroll
  for (int ff = 0; ff < 16; ++ff){
    float e = gelu_f((o3[ff]-mean3)*rstd3*hg[f0+ff] + hbb[f0+ff]);
    part += e * hw2[f0+ff];
  }
  red8(part);
  if (chunk == 0){
    float ps = part + hb2[0];
    float spl = fmaxf(ps, 0.f) + log1pf(expf(-fabsf(ps)));
    pt_out[row] = 5.f - 1.5f*den + 0.5f*spl;
  }
}

// ---------------- attention: 4 threads/row partial dots, softmax over 24 ----------------
__global__ __launch_bounds__(256) void k_attn(const float* __restrict__ spatial, const float* __restrict__ pt_in,
    const float* __restrict__ den_in, const float* __restrict__ objp, int ob_stride,
    const float* __restrict__ nsqp, int nq_stride,
    const float* __restrict__ lt, const float* __restrict__ bh, const float* __restrict__ hs,
    float* __restrict__ attn_out){
  int t = threadIdx.x;
  int sub = t & 3, rl = t >> 2;
  int id = blockIdx.x * 64 + rl;
  int b = id >> 11, n = id & 2047;

  float4 sv[8];
  const float4* sp4 = (const float4*)(spatial + (size_t)id * cH + sub * 32);
  #pragma unroll
  for (int i = 0; i < 8; ++i) sv[i] = sp4[i];
  float spn2 = 0.f;
  #pragma unroll
  for (int i = 0; i < 8; ++i) spn2 += sv[i].x*sv[i].x + sv[i].y*sv[i].y + sv[i].z*sv[i].z + sv[i].w*sv[i].w;

  const float* ob = objp + (size_t)b * ob_stride;
  float acc[8];
  #pragma unroll
  for (int o = 0; o < 8; ++o){
    const float4* orow = (const float4*)(ob + (size_t)o * cH + sub * 32);
    float a0=0,a1=0,a2=0,a3=0;
    #pragma unroll
    for (int i = 0; i < 8; ++i){ float4 w4 = orow[i];
      a0 += w4.x*sv[i].x; a1 += w4.y*sv[i].y; a2 += w4.z*sv[i].z; a3 += w4.w*sv[i].w; }
    acc[o] = (a0+a1)+(a2+a3);
  }
  spn2 += __shfl_xor(spn2, 1); spn2 += __shfl_xor(spn2, 2);
  #pragma unroll
  for (int o = 0; o < 8; ++o){ acc[o] += __shfl_xor(acc[o], 1); acc[o] += __shfl_xor(acc[o], 2); }

  if (sub != 0) return;

  const float* nq = nsqp + (size_t)b * nq_stride;
  float nsqv_[8];
  #pragma unroll
  for (int o = 0; o < 8; ++o) nsqv_[o] = nq[o];
  float pt = pt_in[id], den = den_in[id];
  float hsv = hs[0];
  float lts[3] = { lt[0], lt[1], lt[2] };
  float bhs[3] = { bh[0], bh[1], bh[2] };

  float logits[24];
  #pragma unroll
  for (int k = 0; k < 24; ++k){
    const int o = k / 3, l = k % 3;
    float dtv = pt - lts[l];
    float dr2 = fmaxf(spn2 + nsqv_[o] - 2.f * acc[o], 0.f);
    float ls  = dtv*dtv - dr2;
    float adL = sqrtf(fabsf(ls) + 1e-6f);
    float r   = sqrtf(dr2);
    float adt = fabsf(dtv);
    float hz  = fminf(fmaxf(bhs[l] + hsv * (den - 0.5f), 0.1f), 1.0f);
    float cone = hz - r / (adt + 1e-6f) - 10.f * fmaxf(-dtv, 0.f) - 5.f * fmaxf(r - adt, 0.f);
    logits[k] = (-adL + 0.5f * tanhf(cone)) * 10.f;
  }
  float mx = -3e38f;
  #pragma unroll
  for (int k = 0; k < 24; ++k) mx = fmaxf(mx, logits[k]);
  float es[24]; float ssum = 0.f;
  #pragma unroll
  for (int k = 0; k < 24; ++k){ es[k] = expf(logits[k] - mx); ssum += es[k]; }
  float inv = 1.f / ssum;
  float* ao = attn_out + (size_t)b * cK * cN + n;
  #pragma unroll
  for (int k = 0; k < 24; ++k) ao[(size_t)k * cN] = es[k] * inv;
}

// ---------------- upd[b,k,h] += sum_n attn*spatial ; S[b,k] += sum_n attn ----------------
// grid: b(8) x chunk(32 of 64 n); attn chunk staged in LDS (broadcast reads).
__global__ __launch_bounds__(256) void k_upd(const float* __restrict__ spatial, const float* __restrict__ attn,
                                             float* __restrict__ upd_raw, float* __restrict__ Ssum){
  __shared__ float abuf[24][64];
  int blk = blockIdx.x;
  int b = blk >> 5, chunk = blk & 31;
  int n0 = chunk * 64;
  int t = threadIdx.x;
  const float* ab = attn + (size_t)b * cK * cN + n0;
  #pragma unroll
  for (int i = 0; i < 6; ++i){
    int idx = t + i * 256;
    abuf[idx >> 6][idx & 63] = ab[(size_t)(idx >> 6) * cN + (idx & 63)];
  }
  __syncthreads();
  int h = t & 127, g = t >> 7;
  float acc[12];
  #pragma unroll
  for (int kk = 0; kk < 12; ++kk) acc[kk] = 0.f;
  const float* sp = spatial + ((size_t)b * cN + n0) * cH + h;
  for (int ni = 0; ni < 64; ++ni){
    float spv = sp[(size_t)ni * cH];
    #pragma unroll
    for (int kk = 0; kk < 12; ++kk) acc[kk] += abuf[g*12+kk][ni] * spv;
  }
  #pragma unroll
  for (int kk = 0; kk < 12; ++kk)
    atomicAdd(&upd_raw[((size_t)b * cK + g*12+kk) * cH + h], acc[kk]);
  if (t < 24){
    float s = 0.f;
    #pragma unroll
    for (int j = 0; j < 64; ++j) s += abuf[t][j];
    atomicAdd(&Ssum[b * cK + t], s);
  }
}

// ---------------- GRU + LN + MLP residual ----------------
__global__ __launch_bounds__(128) void k_gru(const float* __restrict__ upd_raw, const float* __restrict__ Ssum,
    const float* __restrict__ ghs, const float* __restrict__ objsp,
    const float* __restrict__ w_ih, const float* __restrict__ b_ih,
    const float* __restrict__ mw1, const float* __restrict__ mb1,
    const float* __restrict__ mw2, const float* __restrict__ mb2,
    const float* __restrict__ ng_, const float* __restrict__ nb_,
    const float* __restrict__ lt,
    float* __restrict__ newobj, float* __restrict__ nsq,
    float* __restrict__ slots_out, int writeSlots){
  __shared__ float ubuf[cH], lbuf[cH], gbuf[cH], red[8];
  int bo = blockIdx.x; int b = bo >> 3, o = bo & 7;
  int t = threadIdx.x;
  int lane = t & 63, wid = t >> 6;

  float u = 0.f;
  #pragma unroll
  for (int l = 0; l < 3; ++l){
    int k = o * 3 + l;
    float s = Ssum[b * cK + k] + 1e-8f;
    u += upd_raw[((size_t)b * cK + k) * cH + t] / s;
  }
  ubuf[t] = u;
  __syncthreads();

  float gi[3];
  #pragma unroll
  for (int j3 = 0; j3 < 3; ++j3){
    const float* wr = w_ih + ((size_t)j3 * cH + t) * cH;
    float a0=0,a1=0,a2=0,a3=0;
    #pragma unroll
    for (int d = 0; d < cH; d += 4){
      a0 += wr[d]*ubuf[d]; a1 += wr[d+1]*ubuf[d+1]; a2 += wr[d+2]*ubuf[d+2]; a3 += wr[d+3]*ubuf[d+3];
    }
    gi[j3] = (a0+a1)+(a2+a3) + b_ih[j3 * cH + t];
  }
  const float* gh = ghs + (size_t)o * 3 * cH;
  float ghr = gh[t], ghz = gh[cH + t], ghn = gh[2 * cH + t];
  float oldv = objsp[(size_t)o * cH + t];
  float rg = 1.f / (1.f + expf(-(gi[0] + ghr)));
  float zg = 1.f / (1.f + expf(-(gi[1] + ghz)));
  float ngv = tanhf(gi[2] + rg * ghn);
  float nv = (1.f - zg) * ngv + zg * oldv;

  float s1 = nv, s2 = nv * nv;
  #pragma unroll
  for (int m = 1; m < 64; m <<= 1){ s1 += __shfl_xor(s1, m); s2 += __shfl_xor(s2, m); }
  if (lane == 0){ red[wid] = s1; red[4 + wid] = s2; }
  __syncthreads();
  float mean = (red[0] + red[1]) * (1.f/128.f);
  float var  = (red[4] + red[5]) * (1.f/128.f) - mean * mean;
  float ln = (nv - mean) * rsqrtf(var + 1e-5f) * ng_[t] + nb_[t];
  lbuf[t] = ln;
  __syncthreads();

  const float* w1r = mw1 + (size_t)t * cH;
  {
    float a0=0,a1=0,a2=0,a3=0;
    #pragma unroll
    for (int d = 0; d < cH; d += 4){
      a0 += w1r[d]*lbuf[d]; a1 += w1r[d+1]*lbuf[d+1]; a2 += w1r[d+2]*lbuf[d+2]; a3 += w1r[d+3]*lbuf[d+3];
    }
    gbuf[t] = gelu_f((a0+a1)+(a2+a3) + mb1[t]);
  }
  __syncthreads();
  const float* w2r = mw2 + (size_t)t * cH;
  float m2v;
  {
    float a0=0,a1=0,a2=0,a3=0;
    #pragma unroll
    for (int d = 0; d < cH; d += 4){
      a0 += w2r[d]*gbuf[d]; a1 += w2r[d+1]*gbuf[d+1]; a2 += w2r[d+2]*gbuf[d+2]; a3 += w2r[d+3]*gbuf[d+3];
    }
    m2v = (a0+a1)+(a2+a3) + mb2[t];
  }
  float outv = nv + 0.2f * m2v;
  newobj[((size_t)b * cO + o) * cH + t] = outv;

  float qv = outv * outv;
  #pragma unroll
  for (int m = 1; m < 64; m <<= 1) qv += __shfl_xor(qv, m);
  __syncthreads();
  if (lane == 0) red[wid] = qv;
  __syncthreads();
  if (t == 0) nsq[b * cO + o] = red[0] + red[1];

  if (writeSlots){
    #pragma unroll
    for (int l = 0; l < 3; ++l){
      size_t base = ((size_t)b * cK + o * 3 + l) * 129;
      slots_out[base + 1 + t] = outv;
      if (t == 0) slots_out[base] = lt[l];
    }
  }
}

extern "C" void kernel_launch(void* const* d_in, const int* in_sizes, int n_in,
                              void* d_out, int out_size, void* d_ws, size_t ws_size,
                              hipStream_t stream){
  const float* x       = (const float*)d_in[0];
  const float* enc_w1  = (const float*)d_in[1];
  const float* enc_b1  = (const float*)d_in[2];
  const float* enc_g1  = (const float*)d_in[3];
  const float* enc_bb1 = (const float*)d_in[4];
  const float* enc_w2  = (const float*)d_in[5];
  const float* enc_b2  = (const float*)d_in[6];
  const float* enc_g2  = (const float*)d_in[7];
  const float* enc_bb2 = (const float*)d_in[8];
  const float* sp_w1   = (const float*)d_in[9];
  const float* sp_b1   = (const float*)d_in[10];
  const float* sp_g    = (const float*)d_in[11];
  const float* sp_bb   = (const float*)d_in[12];
  const float* sp_w2   = (const float*)d_in[13];
  const float* sp_b2   = (const float*)d_in[14];
  const float* objsp   = (const float*)d_in[15];
  const float* hscale  = (const float*)d_in[16];
  const float* ltimes  = (const float*)d_in[17];
  const float* bhor    = (const float*)d_in[18];
  const float* gw_ih   = (const float*)d_in[19];
  const float* gw_hh   = (const float*)d_in[20];
  const float* gb_ih   = (const float*)d_in[21];
  const float* gb_hh   = (const float*)d_in[22];
  const float* mw1     = (const float*)d_in[23];
  const float* mb1     = (const float*)d_in[24];
  const float* mw2     = (const float*)d_in[25];
  const float* mb2     = (const float*)d_in[26];
  const float* normg   = (const float*)d_in[27];
  const float* normb   = (const float*)d_in[28];
  (void)in_sizes; (void)n_in; (void)out_size; (void)ws_size;

  float* out = (float*)d_out;
  float* ws  = (float*)d_ws;

  float* spatial = ws + WS_SPATIAL;
  float* sq      = ws + WS_SQ;
  float* ghs     = ws + WS_GHS;
  float* nsq0    = ws + WS_NSQ0;
  float* newobj  = ws + WS_NEWOBJ;
  float* nsqv    = ws + WS_NSQ;
  float* spw1p   = ws + WS_SPW1P;
  float* updr3   = ws + WS_UPD3;
  float* Ss3     = ws + WS_S3;

  // zero all 3 iterations' accumulators in one shot (UPD3 and S3 are contiguous)
  hipMemsetAsync((void*)updr3, 0, (size_t)(3 * cB * cK * cH + 3 * cB * cK) * sizeof(float), stream);

  k_sq<<<dim3(ROWS / 256), dim3(256), 0, stream>>>(x, sq);
  k_prep<<<dim3(77), dim3(256), 0, stream>>>(objsp, gw_hh, gb_hh, sp_w1, ghs, nsq0, spw1p);
  k_pairwise<<<dim3(cB * (cN / 16)), dim3(256), 0, stream>>>(x, sq, out + OUT_DEN);
  k_enc_head<<<dim3(ROWS / 32), dim3(256), 0, stream>>>(x, out + OUT_DEN,
      enc_w1, enc_b1, enc_g1, enc_bb1, enc_w2, enc_b2, enc_g2, enc_bb2,
      spw1p, sp_b1, sp_g, sp_bb, sp_w2, sp_b2,
      spatial, out + OUT_PT);

  for (int it = 0; it < 3; ++it){
    float* updr = updr3 + (size_t)it * cB * cK * cH;
    float* Ss   = Ss3 + (size_t)it * cB * cK;
    const float* objp = (it == 0) ? objsp : newobj;
    int obst = (it == 0) ? 0 : cO * cH;
    const float* nqp = (it == 0) ? nsq0 : nsqv;
    int nqst = (it == 0) ? 0 : cO;
    k_attn<<<dim3(ROWS / 64), dim3(256), 0, stream>>>(spatial, out + OUT_PT, out + OUT_DEN,
                                                      objp, obst, nqp, nqst,
                                                      ltimes, bhor, hscale, out + OUT_ATTN);
    k_upd<<<dim3(cB * 32), dim3(256), 0, stream>>>(spatial, out + OUT_ATTN, updr, Ss);
    k_gru<<<dim3(cB * cO), dim3(128), 0, stream>>>(updr, Ss, ghs, objsp, gw_ih, gb_ih,
                                                   mw1, mb1, mw2, mb2, normg, normb, ltimes,
                                                   newobj, nsqv, out + OUT_SLOTS, (it == 2) ? 1 : 0);
  }
}

// Round 4
// 626.060 us; speedup vs baseline: 1.7209x; 1.3006x over previous
//
#include <hip/hip_runtime.h>
#include <math.h>

// ---- problem dims ----
constexpr int cB = 8, cN = 2048, cI = 64, cH = 128, cO = 8, cK = 24;
constexpr int ROWS = cB * cN; // 16384

// ---- ws layout (floats) ----
constexpr size_t WS_SPATIAL = 0;                                  // 16384*128
constexpr size_t WS_SQ      = WS_SPATIAL + (size_t)ROWS * cH;     // 16384
constexpr size_t WS_GHS     = WS_SQ + ROWS;                       // 8*384
constexpr size_t WS_NSQ0    = WS_GHS + (size_t)cO * 3 * cH;       // 8
constexpr size_t WS_NEWOBJ  = WS_NSQ0 + cO;                       // 8*8*128
constexpr size_t WS_NSQ     = WS_NEWOBJ + (size_t)cB * cO * cH;   // 64
constexpr size_t WS_SPW1P   = WS_NSQ + (size_t)cB * cO;           // 128*132 padded sp_w1
constexpr size_t WS_UPD3    = WS_SPW1P + (size_t)cH * 132;        // 3*8*24*128
constexpr size_t WS_S3      = WS_UPD3 + (size_t)3 * cB * cK * cH; // 3*8*24 (contiguous after UPD3)

// ---- d_out layout (floats), return order: slots, attn, pred_time, density ----
constexpr size_t OUT_SLOTS = 0;                                   // 8*24*129
constexpr size_t OUT_ATTN  = (size_t)cB * cK * 129;
constexpr size_t OUT_PT    = OUT_ATTN + (size_t)cB * cK * cN;
constexpr size_t OUT_DEN   = OUT_PT + (size_t)cB * cN;

typedef __attribute__((ext_vector_type(8))) short bf16x8;
typedef __attribute__((ext_vector_type(4))) float f32x4;

__device__ __forceinline__ float gelu_f(float v){
  return 0.5f * v * (1.f + erff(v * 0.70710678118654752440f));
}
__device__ __forceinline__ short f2bf(float f){
  unsigned u = __float_as_uint(f);
  u += 0x7fffu + ((u >> 16) & 1u);   // RNE
  return (short)(u >> 16);
}
__device__ __forceinline__ bf16x8 pack8(float4 a, float4 b){
  bf16x8 r;
  r[0]=f2bf(a.x); r[1]=f2bf(a.y); r[2]=f2bf(a.z); r[3]=f2bf(a.w);
  r[4]=f2bf(b.x); r[5]=f2bf(b.y); r[6]=f2bf(b.z); r[7]=f2bf(b.w);
  return r;
}
__device__ __forceinline__ void red8(float& a){   // sum over 8-lane group (masks 1,2,4)
  a += __shfl_xor(a, 1); a += __shfl_xor(a, 2); a += __shfl_xor(a, 4);
}

// ---------------- sq[b,n] = ||x||^2 ----------------
__global__ __launch_bounds__(256) void k_sq(const float* __restrict__ x, float* __restrict__ sq){
  int r = blockIdx.x * 256 + threadIdx.x;
  if (r >= ROWS) return;
  const float4* xp = (const float4*)(x + (size_t)r * cI);
  float s = 0.f;
  #pragma unroll
  for (int i = 0; i < 16; ++i){ float4 v = xp[i]; s += v.x*v.x + v.y*v.y + v.z*v.z + v.w*v.w; }
  sq[r] = s;
}

// ---------------- prep: ghs (b-independent GRU gh), ||obj||^2, padded sp_w1 ----------------
__global__ __launch_bounds__(256) void k_prep(const float* __restrict__ objsp, const float* __restrict__ w_hh,
                                              const float* __restrict__ b_hh, const float* __restrict__ spw1,
                                              float* __restrict__ ghs, float* __restrict__ nsq0,
                                              float* __restrict__ spw1p){
  int id = blockIdx.x * 256 + threadIdx.x;
  if (id < cO * 3 * cH){
    int o = id / (3 * cH), j = id % (3 * cH);
    const float* wr = w_hh + (size_t)j * cH;
    const float* ob = objsp + (size_t)o * cH;
    float a0=0,a1=0,a2=0,a3=0;
    #pragma unroll
    for (int h = 0; h < cH; h += 4){
      a0 += wr[h]*ob[h]; a1 += wr[h+1]*ob[h+1]; a2 += wr[h+2]*ob[h+2]; a3 += wr[h+3]*ob[h+3];
    }
    ghs[id] = (a0+a1)+(a2+a3) + b_hh[j];
  } else if (id < cO * 3 * cH + cO){
    int o = id - cO * 3 * cH;
    const float* ob = objsp + (size_t)o * cH;
    float s = 0.f;
    for (int h = 0; h < cH; ++h) s += ob[h]*ob[h];
    nsq0[o] = s;
  } else {
    int idx = id - (cO * 3 * cH + cO);
    if (idx < cH * 129){
      int f = idx / 129, d = idx % 129;
      spw1p[(size_t)f * 132 + d] = spw1[idx];
    }
  }
}

// ---------------- pairwise distances (bf16 MFMA) + fused per-row top-6 -> density ----------------
__global__ __launch_bounds__(256) void k_pairwise(const float* __restrict__ x, const float* __restrict__ sq,
                                                  float* __restrict__ den_out){
  __shared__ float cand[4][16][96];
  int b  = blockIdx.x >> 7;
  int rt = blockIdx.x & 127;
  int r0 = rt * 16;
  int lane = threadIdx.x & 63, w = threadIdx.x >> 6;
  const float* xb = x + (size_t)b * cN * cI;

  int arow = r0 + (lane & 15);
  int koff = (lane >> 4) * 8;
  const float4* ap = (const float4*)(xb + (size_t)arow * cI + koff);
  bf16x8 a0 = pack8(ap[0], ap[1]);
  bf16x8 a1 = pack8(ap[8], ap[9]);

  float sqr[4];
  int rg0 = r0 + ((lane >> 4) << 2);
  #pragma unroll
  for (int j = 0; j < 4; ++j) sqr[j] = sq[b * cN + rg0 + j];

  float t[4][6];
  #pragma unroll
  for (int j = 0; j < 4; ++j){
    #pragma unroll
    for (int q = 0; q < 6; ++q) t[j][q] = 3e38f;
  }

  int cbase = w * 512;
  for (int ct = 0; ct < 32; ++ct){
    int col0 = cbase + ct * 16;
    int brow = col0 + (lane & 15);
    const float4* bp = (const float4*)(xb + (size_t)brow * cI + koff);
    bf16x8 b0 = pack8(bp[0], bp[1]);
    bf16x8 b1 = pack8(bp[8], bp[9]);
    f32x4 acc = {0.f, 0.f, 0.f, 0.f};
    acc = __builtin_amdgcn_mfma_f32_16x16x32_bf16(a0, b0, acc, 0, 0, 0);
    acc = __builtin_amdgcn_mfma_f32_16x16x32_bf16(a1, b1, acc, 0, 0, 0);
    float sqc = sq[b * cN + col0 + (lane & 15)];
    #pragma unroll
    for (int j = 0; j < 4; ++j){
      float d2 = sqr[j] + sqc - 2.f * acc[j];
      d2 = fmaxf(d2, 0.f);
      if (d2 < t[j][5]){
        if (d2 < t[j][4]){ t[j][5]=t[j][4];
          if (d2 < t[j][3]){ t[j][4]=t[j][3];
            if (d2 < t[j][2]){ t[j][3]=t[j][2];
              if (d2 < t[j][1]){ t[j][2]=t[j][1];
                if (d2 < t[j][0]){ t[j][1]=t[j][0]; t[j][0]=d2; } else t[j][1]=d2;
              } else t[j][2]=d2;
            } else t[j][3]=d2;
          } else t[j][4]=d2;
        } else t[j][5]=d2;
      }
    }
  }
  int rloc = (lane >> 4) << 2;
  #pragma unroll
  for (int j = 0; j < 4; ++j){
    #pragma unroll
    for (int q = 0; q < 6; ++q) cand[w][rloc + j][(lane & 15) * 6 + q] = t[j][q];
  }
  __syncthreads();
  int tt = threadIdx.x;
  if (tt < 16){
    float m0=3e38f,m1=3e38f,m2=3e38f,m3=3e38f,m4=3e38f,m5=3e38f;
    for (int ww = 0; ww < 4; ++ww){
      const float* c = cand[ww][tt];
      for (int q = 0; q < 96; ++q){
        float v = c[q];
        if (v < m5){
          if (v<m4){ m5=m4; if (v<m3){ m4=m3; if (v<m2){ m3=m2; if (v<m1){ m2=m1; if (v<m0){ m1=m0; m0=v; } else m1=v; } else m2=v; } else m3=v; } else m4=v; } else m5=v;
        }
      }
    }
    float md = (sqrtf(m1)+sqrtf(m2)+sqrtf(m3)+sqrtf(m4)+sqrtf(m5)) * 0.2f;
    den_out[b * cN + r0 + tt] = tanhf(md);
  }
}

// ---------------- fused encoder + spatial head (d-outer accumulate, no big reg arrays) ----------------
// 256 threads = 4 waves; wave owns 8 rows; lane: chunk = lane&7 (16 outputs), rsub = lane>>3 (row).
__global__ __launch_bounds__(256) void k_enc_head(const float* __restrict__ x, const float* __restrict__ den_in,
    const float* __restrict__ w1, const float* __restrict__ b1v, const float* __restrict__ g1, const float* __restrict__ bb1,
    const float* __restrict__ w2, const float* __restrict__ b2v, const float* __restrict__ g2, const float* __restrict__ bb2,
    const float* __restrict__ hw1p, const float* __restrict__ hb1, const float* __restrict__ hg, const float* __restrict__ hbb,
    const float* __restrict__ hw2, const float* __restrict__ hb2,
    float* __restrict__ spatial, float* __restrict__ pt_out){
  __shared__ __align__(16) float xbuf[32][68];
  __shared__ __align__(16) float hbuf[32][132];
  int t = threadIdx.x;
  int lane = t & 63, wid = t >> 6;
  int chunk = lane & 7, rsub = lane >> 3;
  int rloc = wid * 8 + rsub;
  int row0 = blockIdx.x * 32;
  int row = row0 + rloc;
  const int f0 = chunk * 16;

  // stage 32 x-rows (contiguous 2048 floats) into LDS
  {
    const float4* xs = (const float4*)(x + (size_t)row0 * cI);
    #pragma unroll
    for (int i = 0; i < 2; ++i){
      int idx = t + i * 256;             // 512 float4s
      float4 v = xs[idx];
      *(float4*)&xbuf[idx >> 4][(idx & 15) * 4] = v;
    }
  }
  __syncthreads();

  // ---- layer 1: x(64) -> 16 outputs, d-outer ----
  float acc[16];
  #pragma unroll
  for (int ff = 0; ff < 16; ++ff) acc[ff] = b1v[f0 + ff];
  const float4* xin = (const float4*)xbuf[rloc];
  #pragma unroll 2
  for (int dc = 0; dc < 16; ++dc){
    float4 in4 = xin[dc];
    #pragma unroll
    for (int ff = 0; ff < 16; ++ff){
      float4 w4 = *(const float4*)(w1 + (size_t)(f0 + ff) * cI + dc * 4);
      acc[ff] += w4.x*in4.x + w4.y*in4.y + w4.z*in4.z + w4.w*in4.w;
    }
  }
  float sm = 0.f, s2 = 0.f;
  #pragma unroll
  for (int ff = 0; ff < 16; ++ff){ sm += acc[ff]; s2 += acc[ff]*acc[ff]; }
  red8(sm); red8(s2);
  float mean = sm * (1.f/128.f);
  float rstd = rsqrtf(s2 * (1.f/128.f) - mean*mean + 1e-5f);
  #pragma unroll
  for (int ff = 0; ff < 16; ++ff)
    hbuf[rloc][f0+ff] = gelu_f((acc[ff]-mean)*rstd*g1[f0+ff] + bb1[f0+ff]);
  __syncthreads();

  // ---- layer 2: h(128) -> 16 outputs, d-outer ----
  #pragma unroll
  for (int ff = 0; ff < 16; ++ff) acc[ff] = b2v[f0 + ff];
  const float4* hin = (const float4*)hbuf[rloc];
  #pragma unroll 2
  for (int dc = 0; dc < 32; ++dc){
    float4 in4 = hin[dc];
    #pragma unroll
    for (int ff = 0; ff < 16; ++ff){
      float4 w4 = *(const float4*)(w2 + (size_t)(f0 + ff) * cH + dc * 4);
      acc[ff] += w4.x*in4.x + w4.y*in4.y + w4.z*in4.z + w4.w*in4.w;
    }
  }
  sm = 0.f; s2 = 0.f;
  #pragma unroll
  for (int ff = 0; ff < 16; ++ff){ sm += acc[ff]; s2 += acc[ff]*acc[ff]; }
  red8(sm); red8(s2);
  float mean2 = sm * (1.f/128.f);
  float rstd2 = rsqrtf(s2 * (1.f/128.f) - mean2*mean2 + 1e-5f);
  float sv16[16];
  #pragma unroll
  for (int ff = 0; ff < 16; ++ff)
    sv16[ff] = (acc[ff]-mean2)*rstd2*g2[f0+ff] + bb2[f0+ff];
  float* srow = spatial + (size_t)row * cH + f0;
  #pragma unroll
  for (int ff = 0; ff < 16; ff += 4){
    float4 v = { sv16[ff], sv16[ff+1], sv16[ff+2], sv16[ff+3] };
    *(float4*)(srow + ff) = v;
  }
  __syncthreads();
  #pragma unroll
  for (int ff = 0; ff < 16; ++ff) hbuf[rloc][f0+ff] = sv16[ff];
  __syncthreads();

  // ---- head layer 1: [spatial(128), den] -> 16 outputs, d-outer ----
  float den = den_in[row];
  #pragma unroll
  for (int ff = 0; ff < 16; ++ff)
    acc[ff] = hw1p[(size_t)(f0+ff) * 132 + 128] * den + hb1[f0+ff];
  #pragma unroll 2
  for (int dc = 0; dc < 32; ++dc){
    float4 in4 = hin[dc];
    #pragma unroll
    for (int ff = 0; ff < 16; ++ff){
      float4 w4 = *(const float4*)(hw1p + (size_t)(f0 + ff) * 132 + dc * 4);
      acc[ff] += w4.x*in4.x + w4.y*in4.y + w4.z*in4.z + w4.w*in4.w;
    }
  }
  sm = 0.f; s2 = 0.f;
  #pragma unroll
  for (int ff = 0; ff < 16; ++ff){ sm += acc[ff]; s2 += acc[ff]*acc[ff]; }
  red8(sm); red8(s2);
  float mean3 = sm * (1.f/128.f);
  float rstd3 = rsqrtf(s2 * (1.f/128.f) - mean3*mean3 + 1e-5f);
  float part = 0.f;
  #pragma unroll
  for (int ff = 0; ff < 16; ++ff){
    float e = gelu_f((acc[ff]-mean3)*rstd3*hg[f0+ff] + hbb[f0+ff]);
    part += e * hw2[f0+ff];
  }
  red8(part);
  if (chunk == 0){
    float ps = part + hb2[0];
    float spl = fmaxf(ps, 0.f) + log1pf(expf(-fabsf(ps)));
    pt_out[row] = 5.f - 1.5f*den + 0.5f*spl;
  }
}

// ---------------- attention: 4 threads/row partial dots, softmax over 24 ----------------
__global__ __launch_bounds__(256) void k_attn(const float* __restrict__ spatial, const float* __restrict__ pt_in,
    const float* __restrict__ den_in, const float* __restrict__ objp, int ob_stride,
    const float* __restrict__ nsqp, int nq_stride,
    const float* __restrict__ lt, const float* __restrict__ bh, const float* __restrict__ hs,
    float* __restrict__ attn_out){
  int t = threadIdx.x;
  int sub = t & 3, rl = t >> 2;
  int id = blockIdx.x * 64 + rl;
  int b = id >> 11, n = id & 2047;

  float4 sv[8];
  const float4* sp4 = (const float4*)(spatial + (size_t)id * cH + sub * 32);
  #pragma unroll
  for (int i = 0; i < 8; ++i) sv[i] = sp4[i];
  float spn2 = 0.f;
  #pragma unroll
  for (int i = 0; i < 8; ++i) spn2 += sv[i].x*sv[i].x + sv[i].y*sv[i].y + sv[i].z*sv[i].z + sv[i].w*sv[i].w;

  const float* ob = objp + (size_t)b * ob_stride;
  float acc[8];
  #pragma unroll
  for (int o = 0; o < 8; ++o){
    const float4* orow = (const float4*)(ob + (size_t)o * cH + sub * 32);
    float a0=0,a1=0,a2=0,a3=0;
    #pragma unroll
    for (int i = 0; i < 8; ++i){ float4 w4 = orow[i];
      a0 += w4.x*sv[i].x; a1 += w4.y*sv[i].y; a2 += w4.z*sv[i].z; a3 += w4.w*sv[i].w; }
    acc[o] = (a0+a1)+(a2+a3);
  }
  spn2 += __shfl_xor(spn2, 1); spn2 += __shfl_xor(spn2, 2);
  #pragma unroll
  for (int o = 0; o < 8; ++o){ acc[o] += __shfl_xor(acc[o], 1); acc[o] += __shfl_xor(acc[o], 2); }

  if (sub != 0) return;

  const float* nq = nsqp + (size_t)b * nq_stride;
  float nsqv_[8];
  #pragma unroll
  for (int o = 0; o < 8; ++o) nsqv_[o] = nq[o];
  float pt = pt_in[id], den = den_in[id];
  float hsv = hs[0];
  float lts[3] = { lt[0], lt[1], lt[2] };
  float bhs[3] = { bh[0], bh[1], bh[2] };

  float logits[24];
  #pragma unroll
  for (int k = 0; k < 24; ++k){
    const int o = k / 3, l = k % 3;
    float dtv = pt - lts[l];
    float dr2 = fmaxf(spn2 + nsqv_[o] - 2.f * acc[o], 0.f);
    float ls  = dtv*dtv - dr2;
    float adL = sqrtf(fabsf(ls) + 1e-6f);
    float r   = sqrtf(dr2);
    float adt = fabsf(dtv);
    float hz  = fminf(fmaxf(bhs[l] + hsv * (den - 0.5f), 0.1f), 1.0f);
    float cone = hz - r / (adt + 1e-6f) - 10.f * fmaxf(-dtv, 0.f) - 5.f * fmaxf(r - adt, 0.f);
    logits[k] = (-adL + 0.5f * tanhf(cone)) * 10.f;
  }
  float mx = -3e38f;
  #pragma unroll
  for (int k = 0; k < 24; ++k) mx = fmaxf(mx, logits[k]);
  float es[24]; float ssum = 0.f;
  #pragma unroll
  for (int k = 0; k < 24; ++k){ es[k] = expf(logits[k] - mx); ssum += es[k]; }
  float inv = 1.f / ssum;
  float* ao = attn_out + (size_t)b * cK * cN + n;
  #pragma unroll
  for (int k = 0; k < 24; ++k) ao[(size_t)k * cN] = es[k] * inv;
}

// ---------------- upd[b,k,h] += sum_n attn*spatial ; S[b,k] += sum_n attn ----------------
__global__ __launch_bounds__(256) void k_upd(const float* __restrict__ spatial, const float* __restrict__ attn,
                                             float* __restrict__ upd_raw, float* __restrict__ Ssum){
  __shared__ float abuf[24][64];
  int blk = blockIdx.x;
  int b = blk >> 5, chunk = blk & 31;
  int n0 = chunk * 64;
  int t = threadIdx.x;
  const float* ab = attn + (size_t)b * cK * cN + n0;
  #pragma unroll
  for (int i = 0; i < 6; ++i){
    int idx = t + i * 256;
    abuf[idx >> 6][idx & 63] = ab[(size_t)(idx >> 6) * cN + (idx & 63)];
  }
  __syncthreads();
  int h = t & 127, g = t >> 7;
  float acc[12];
  #pragma unroll
  for (int kk = 0; kk < 12; ++kk) acc[kk] = 0.f;
  const float* sp = spatial + ((size_t)b * cN + n0) * cH + h;
  for (int ni = 0; ni < 64; ++ni){
    float spv = sp[(size_t)ni * cH];
    #pragma unroll
    for (int kk = 0; kk < 12; ++kk) acc[kk] += abuf[g*12+kk][ni] * spv;
  }
  #pragma unroll
  for (int kk = 0; kk < 12; ++kk)
    atomicAdd(&upd_raw[((size_t)b * cK + g*12+kk) * cH + h], acc[kk]);
  if (t < 24){
    float s = 0.f;
    #pragma unroll
    for (int j = 0; j < 64; ++j) s += abuf[t][j];
    atomicAdd(&Ssum[b * cK + t], s);
  }
}

// ---------------- GRU + LN + MLP residual ----------------
__global__ __launch_bounds__(128) void k_gru(const float* __restrict__ upd_raw, const float* __restrict__ Ssum,
    const float* __restrict__ ghs, const float* __restrict__ objsp,
    const float* __restrict__ w_ih, const float* __restrict__ b_ih,
    const float* __restrict__ mw1, const float* __restrict__ mb1,
    const float* __restrict__ mw2, const float* __restrict__ mb2,
    const float* __restrict__ ng_, const float* __restrict__ nb_,
    const float* __restrict__ lt,
    float* __restrict__ newobj, float* __restrict__ nsq,
    float* __restrict__ slots_out, int writeSlots){
  __shared__ float ubuf[cH], lbuf[cH], gbuf[cH], red[8];
  int bo = blockIdx.x; int b = bo >> 3, o = bo & 7;
  int t = threadIdx.x;
  int lane = t & 63, wid = t >> 6;

  float u = 0.f;
  #pragma unroll
  for (int l = 0; l < 3; ++l){
    int k = o * 3 + l;
    float s = Ssum[b * cK + k] + 1e-8f;
    u += upd_raw[((size_t)b * cK + k) * cH + t] / s;
  }
  ubuf[t] = u;
  __syncthreads();

  float gi[3];
  #pragma unroll
  for (int j3 = 0; j3 < 3; ++j3){
    const float* wr = w_ih + ((size_t)j3 * cH + t) * cH;
    float a0=0,a1=0,a2=0,a3=0;
    #pragma unroll
    for (int d = 0; d < cH; d += 4){
      a0 += wr[d]*ubuf[d]; a1 += wr[d+1]*ubuf[d+1]; a2 += wr[d+2]*ubuf[d+2]; a3 += wr[d+3]*ubuf[d+3];
    }
    gi[j3] = (a0+a1)+(a2+a3) + b_ih[j3 * cH + t];
  }
  const float* gh = ghs + (size_t)o * 3 * cH;
  float ghr = gh[t], ghz = gh[cH + t], ghn = gh[2 * cH + t];
  float oldv = objsp[(size_t)o * cH + t];
  float rg = 1.f / (1.f + expf(-(gi[0] + ghr)));
  float zg = 1.f / (1.f + expf(-(gi[1] + ghz)));
  float ngv = tanhf(gi[2] + rg * ghn);
  float nv = (1.f - zg) * ngv + zg * oldv;

  float s1 = nv, s2 = nv * nv;
  #pragma unroll
  for (int m = 1; m < 64; m <<= 1){ s1 += __shfl_xor(s1, m); s2 += __shfl_xor(s2, m); }
  if (lane == 0){ red[wid] = s1; red[4 + wid] = s2; }
  __syncthreads();
  float mean = (red[0] + red[1]) * (1.f/128.f);
  float var  = (red[4] + red[5]) * (1.f/128.f) - mean * mean;
  float ln = (nv - mean) * rsqrtf(var + 1e-5f) * ng_[t] + nb_[t];
  lbuf[t] = ln;
  __syncthreads();

  const float* w1r = mw1 + (size_t)t * cH;
  {
    float a0=0,a1=0,a2=0,a3=0;
    #pragma unroll
    for (int d = 0; d < cH; d += 4){
      a0 += w1r[d]*lbuf[d]; a1 += w1r[d+1]*lbuf[d+1]; a2 += w1r[d+2]*lbuf[d+2]; a3 += w1r[d+3]*lbuf[d+3];
    }
    gbuf[t] = gelu_f((a0+a1)+(a2+a3) + mb1[t]);
  }
  __syncthreads();
  const float* w2r = mw2 + (size_t)t * cH;
  float m2v;
  {
    float a0=0,a1=0,a2=0,a3=0;
    #pragma unroll
    for (int d = 0; d < cH; d += 4){
      a0 += w2r[d]*gbuf[d]; a1 += w2r[d+1]*gbuf[d+1]; a2 += w2r[d+2]*gbuf[d+2]; a3 += w2r[d+3]*gbuf[d+3];
    }
    m2v = (a0+a1)+(a2+a3) + mb2[t];
  }
  float outv = nv + 0.2f * m2v;
  newobj[((size_t)b * cO + o) * cH + t] = outv;

  float qv = outv * outv;
  #pragma unroll
  for (int m = 1; m < 64; m <<= 1) qv += __shfl_xor(qv, m);
  __syncthreads();
  if (lane == 0) red[wid] = qv;
  __syncthreads();
  if (t == 0) nsq[b * cO + o] = red[0] + red[1];

  if (writeSlots){
    #pragma unroll
    for (int l = 0; l < 3; ++l){
      size_t base = ((size_t)b * cK + o * 3 + l) * 129;
      slots_out[base + 1 + t] = outv;
      if (t == 0) slots_out[base] = lt[l];
    }
  }
}

extern "C" void kernel_launch(void* const* d_in, const int* in_sizes, int n_in,
                              void* d_out, int out_size, void* d_ws, size_t ws_size,
                              hipStream_t stream){
  const float* x       = (const float*)d_in[0];
  const float* enc_w1  = (const float*)d_in[1];
  const float* enc_b1  = (const float*)d_in[2];
  const float* enc_g1  = (const float*)d_in[3];
  const float* enc_bb1 = (const float*)d_in[4];
  const float* enc_w2  = (const float*)d_in[5];
  const float* enc_b2  = (const float*)d_in[6];
  const float* enc_g2  = (const float*)d_in[7];
  const float* enc_bb2 = (const float*)d_in[8];
  const float* sp_w1   = (const float*)d_in[9];
  const float* sp_b1   = (const float*)d_in[10];
  const float* sp_g    = (const float*)d_in[11];
  const float* sp_bb   = (const float*)d_in[12];
  const float* sp_w2   = (const float*)d_in[13];
  const float* sp_b2   = (const float*)d_in[14];
  const float* objsp   = (const float*)d_in[15];
  const float* hscale  = (const float*)d_in[16];
  const float* ltimes  = (const float*)d_in[17];
  const float* bhor    = (const float*)d_in[18];
  const float* gw_ih   = (const float*)d_in[19];
  const float* gw_hh   = (const float*)d_in[20];
  const float* gb_ih   = (const float*)d_in[21];
  const float* gb_hh   = (const float*)d_in[22];
  const float* mw1     = (const float*)d_in[23];
  const float* mb1     = (const float*)d_in[24];
  const float* mw2     = (const float*)d_in[25];
  const float* mb2     = (const float*)d_in[26];
  const float* normg   = (const float*)d_in[27];
  const float* normb   = (const float*)d_in[28];
  (void)in_sizes; (void)n_in; (void)out_size; (void)ws_size;

  float* out = (float*)d_out;
  float* ws  = (float*)d_ws;

  float* spatial = ws + WS_SPATIAL;
  float* sq      = ws + WS_SQ;
  float* ghs     = ws + WS_GHS;
  float* nsq0    = ws + WS_NSQ0;
  float* newobj  = ws + WS_NEWOBJ;
  float* nsqv    = ws + WS_NSQ;
  float* spw1p   = ws + WS_SPW1P;
  float* updr3   = ws + WS_UPD3;
  float* Ss3     = ws + WS_S3;

  hipMemsetAsync((void*)updr3, 0, (size_t)(3 * cB * cK * cH + 3 * cB * cK) * sizeof(float), stream);

  k_sq<<<dim3(ROWS / 256), dim3(256), 0, stream>>>(x, sq);
  k_prep<<<dim3(77), dim3(256), 0, stream>>>(objsp, gw_hh, gb_hh, sp_w1, ghs, nsq0, spw1p);
  k_pairwise<<<dim3(cB * (cN / 16)), dim3(256), 0, stream>>>(x, sq, out + OUT_DEN);
  k_enc_head<<<dim3(ROWS / 32), dim3(256), 0, stream>>>(x, out + OUT_DEN,
      enc_w1, enc_b1, enc_g1, enc_bb1, enc_w2, enc_b2, enc_g2, enc_bb2,
      spw1p, sp_b1, sp_g, sp_bb, sp_w2, sp_b2,
      spatial, out + OUT_PT);

  for (int it = 0; it < 3; ++it){
    float* updr = updr3 + (size_t)it * cB * cK * cH;
    float* Ss   = Ss3 + (size_t)it * cB * cK;
    const float* objp = (it == 0) ? objsp : newobj;
    int obst = (it == 0) ? 0 : cO * cH;
    const float* nqp = (it == 0) ? nsq0 : nsqv;
    int nqst = (it == 0) ? 0 : cO;
    k_attn<<<dim3(ROWS / 64), dim3(256), 0, stream>>>(spatial, out + OUT_PT, out + OUT_DEN,
                                                      objp, obst, nqp, nqst,
                                                      ltimes, bhor, hscale, out + OUT_ATTN);
    k_upd<<<dim3(cB * 32), dim3(256), 0, stream>>>(spatial, out + OUT_ATTN, updr, Ss);
    k_gru<<<dim3(cB * cO), dim3(128), 0, stream>>>(updr, Ss, ghs, objsp, gw_ih, gb_ih,
                                                   mw1, mb1, mw2, mb2, normg, normb, ltimes,
                                                   newobj, nsqv, out + OUT_SLOTS, (it == 2) ? 1 : 0);
  }
}

// Round 5
// 385.408 us; speedup vs baseline: 2.7955x; 1.6244x over previous
//
#include <hip/hip_runtime.h>
#include <math.h>

// ---- problem dims ----
constexpr int cB = 8, cN = 2048, cI = 64, cH = 128, cO = 8, cK = 24;
constexpr int ROWS = cB * cN; // 16384

// ---- ws layout (floats) ----
constexpr size_t WS_SPATIAL = 0;                                  // 16384*128
constexpr size_t WS_SQ      = WS_SPATIAL + (size_t)ROWS * cH;     // 16384
constexpr size_t WS_GHS     = WS_SQ + ROWS;                       // 8*384
constexpr size_t WS_NSQ0    = WS_GHS + (size_t)cO * 3 * cH;       // 8
constexpr size_t WS_NEWOBJ  = WS_NSQ0 + cO;                       // 8*8*128
constexpr size_t WS_NSQ     = WS_NEWOBJ + (size_t)cB * cO * cH;   // 64
constexpr size_t WS_W1T     = WS_NSQ + (size_t)cB * cO;           // 16*128*4  = 8192
constexpr size_t WS_W2T     = WS_W1T + 8192;                      // 32*128*4  = 16384
constexpr size_t WS_HW1T    = WS_W2T + 16384;                     // 33*128*4  = 16896
constexpr size_t WS_UPD3    = WS_HW1T + 16896;                    // 3*8*24*128
constexpr size_t WS_S3      = WS_UPD3 + (size_t)3 * cB * cK * cH; // 3*8*24

// ---- d_out layout (floats), return order: slots, attn, pred_time, density ----
constexpr size_t OUT_SLOTS = 0;                                   // 8*24*129
constexpr size_t OUT_ATTN  = (size_t)cB * cK * 129;
constexpr size_t OUT_PT    = OUT_ATTN + (size_t)cB * cK * cN;
constexpr size_t OUT_DEN   = OUT_PT + (size_t)cB * cN;

typedef __attribute__((ext_vector_type(8))) short bf16x8;
typedef __attribute__((ext_vector_type(4))) float f32x4;

__device__ __forceinline__ float gelu_f(float v){
  return 0.5f * v * (1.f + erff(v * 0.70710678118654752440f));
}
__device__ __forceinline__ short f2bf(float f){
  unsigned u = __float_as_uint(f);
  u += 0x7fffu + ((u >> 16) & 1u);   // RNE
  return (short)(u >> 16);
}
__device__ __forceinline__ bf16x8 pack8(float4 a, float4 b){
  bf16x8 r;
  r[0]=f2bf(a.x); r[1]=f2bf(a.y); r[2]=f2bf(a.z); r[3]=f2bf(a.w);
  r[4]=f2bf(b.x); r[5]=f2bf(b.y); r[6]=f2bf(b.z); r[7]=f2bf(b.w);
  return r;
}
__device__ __forceinline__ float wred(float a){   // full-wave (64) butterfly sum
  a += __shfl_xor(a, 1); a += __shfl_xor(a, 2); a += __shfl_xor(a, 4);
  a += __shfl_xor(a, 8); a += __shfl_xor(a, 16); a += __shfl_xor(a, 32);
  return a;
}

// ---------------- sq[b,n] = ||x||^2 ----------------
__global__ __launch_bounds__(256) void k_sq(const float* __restrict__ x, float* __restrict__ sq){
  int r = blockIdx.x * 256 + threadIdx.x;
  if (r >= ROWS) return;
  const float4* xp = (const float4*)(x + (size_t)r * cI);
  float s = 0.f;
  #pragma unroll
  for (int i = 0; i < 16; ++i){ float4 v = xp[i]; s += v.x*v.x + v.y*v.y + v.z*v.z + v.w*v.w; }
  sq[r] = s;
}

// ---------------- prep: ghs, ||obj||^2, transposed d-chunked weight copies ----------------
// w*t layout: [dc][f][j] = W[f][dc*4+j]  (f contiguous -> lane-coalesced loads)
__global__ __launch_bounds__(256) void k_prep(const float* __restrict__ objsp, const float* __restrict__ w_hh,
                                              const float* __restrict__ b_hh,
                                              const float* __restrict__ ew1, const float* __restrict__ ew2,
                                              const float* __restrict__ spw1,
                                              float* __restrict__ ghs, float* __restrict__ nsq0,
                                              float* __restrict__ w1t, float* __restrict__ w2t,
                                              float* __restrict__ hw1t){
  int id = blockIdx.x * 256 + threadIdx.x;
  if (id < cO * 3 * cH){
    int o = id / (3 * cH), j = id % (3 * cH);
    const float* wr = w_hh + (size_t)j * cH;
    const float* ob = objsp + (size_t)o * cH;
    float a0=0,a1=0,a2=0,a3=0;
    #pragma unroll
    for (int h = 0; h < cH; h += 4){
      a0 += wr[h]*ob[h]; a1 += wr[h+1]*ob[h+1]; a2 += wr[h+2]*ob[h+2]; a3 += wr[h+3]*ob[h+3];
    }
    ghs[id] = (a0+a1)+(a2+a3) + b_hh[j];
  } else if (id < cO * 3 * cH + cO){
    int o = id - cO * 3 * cH;
    const float* ob = objsp + (size_t)o * cH;
    float s = 0.f;
    for (int h = 0; h < cH; ++h) s += ob[h]*ob[h];
    nsq0[o] = s;
  } else {
    int idx = id - (cO * 3 * cH + cO);
    if (idx < 8192){                       // w1t: 16 dc
      int dc = idx >> 9, rem = idx & 511, f = rem >> 2, j = rem & 3;
      w1t[idx] = ew1[f * cI + dc * 4 + j];
    } else if (idx < 24576){               // w2t: 32 dc
      int k2 = idx - 8192;
      int dc = k2 >> 9, rem = k2 & 511, f = rem >> 2, j = rem & 3;
      w2t[k2] = ew2[f * cH + dc * 4 + j];
    } else if (idx < 41472){               // hw1t: 33 dc (d=128 -> den weight; 129..131 zero)
      int k3 = idx - 24576;
      int dc = k3 >> 9, rem = k3 & 511, f = rem >> 2, j = rem & 3;
      int d = dc * 4 + j;
      hw1t[k3] = (d < 129) ? spw1[f * 129 + d] : 0.f;
    }
  }
}

// ---------------- pairwise distances (bf16 MFMA) + fused per-row top-6 -> density ----------------
__global__ __launch_bounds__(256) void k_pairwise(const float* __restrict__ x, const float* __restrict__ sq,
                                                  float* __restrict__ den_out){
  __shared__ float cand[4][16][96];
  int b  = blockIdx.x >> 7;
  int rt = blockIdx.x & 127;
  int r0 = rt * 16;
  int lane = threadIdx.x & 63, w = threadIdx.x >> 6;
  const float* xb = x + (size_t)b * cN * cI;

  int arow = r0 + (lane & 15);
  int koff = (lane >> 4) * 8;
  const float4* ap = (const float4*)(xb + (size_t)arow * cI + koff);
  bf16x8 a0 = pack8(ap[0], ap[1]);
  bf16x8 a1 = pack8(ap[8], ap[9]);

  float sqr[4];
  int rg0 = r0 + ((lane >> 4) << 2);
  #pragma unroll
  for (int j = 0; j < 4; ++j) sqr[j] = sq[b * cN + rg0 + j];

  float t[4][6];
  #pragma unroll
  for (int j = 0; j < 4; ++j){
    #pragma unroll
    for (int q = 0; q < 6; ++q) t[j][q] = 3e38f;
  }

  int cbase = w * 512;
  for (int ct = 0; ct < 32; ++ct){
    int col0 = cbase + ct * 16;
    int brow = col0 + (lane & 15);
    const float4* bp = (const float4*)(xb + (size_t)brow * cI + koff);
    bf16x8 b0 = pack8(bp[0], bp[1]);
    bf16x8 b1 = pack8(bp[8], bp[9]);
    f32x4 acc = {0.f, 0.f, 0.f, 0.f};
    acc = __builtin_amdgcn_mfma_f32_16x16x32_bf16(a0, b0, acc, 0, 0, 0);
    acc = __builtin_amdgcn_mfma_f32_16x16x32_bf16(a1, b1, acc, 0, 0, 0);
    float sqc = sq[b * cN + col0 + (lane & 15)];
    #pragma unroll
    for (int j = 0; j < 4; ++j){
      float d2 = sqr[j] + sqc - 2.f * acc[j];
      d2 = fmaxf(d2, 0.f);
      if (d2 < t[j][5]){
        if (d2 < t[j][4]){ t[j][5]=t[j][4];
          if (d2 < t[j][3]){ t[j][4]=t[j][3];
            if (d2 < t[j][2]){ t[j][3]=t[j][2];
              if (d2 < t[j][1]){ t[j][2]=t[j][1];
                if (d2 < t[j][0]){ t[j][1]=t[j][0]; t[j][0]=d2; } else t[j][1]=d2;
              } else t[j][2]=d2;
            } else t[j][3]=d2;
          } else t[j][4]=d2;
        } else t[j][5]=d2;
      }
    }
  }
  int rloc = (lane >> 4) << 2;
  #pragma unroll
  for (int j = 0; j < 4; ++j){
    #pragma unroll
    for (int q = 0; q < 6; ++q) cand[w][rloc + j][(lane & 15) * 6 + q] = t[j][q];
  }
  __syncthreads();
  int tt = threadIdx.x;
  if (tt < 16){
    float m0=3e38f,m1=3e38f,m2=3e38f,m3=3e38f,m4=3e38f,m5=3e38f;
    for (int ww = 0; ww < 4; ++ww){
      const float* c = cand[ww][tt];
      for (int q = 0; q < 96; ++q){
        float v = c[q];
        if (v < m5){
          if (v<m4){ m5=m4; if (v<m3){ m4=m3; if (v<m2){ m3=m2; if (v<m1){ m2=m1; if (v<m0){ m1=m0; m0=v; } else m1=v; } else m2=v; } else m3=v; } else m4=v; } else m5=v;
        }
      }
    }
    float md = (sqrtf(m1)+sqrtf(m2)+sqrtf(m3)+sqrtf(m4)+sqrtf(m5)) * 0.2f;
    den_out[b * cN + r0 + tt] = tanhf(md);
  }
}

// ---------------- fused encoder + spatial head (lane-contiguous weights) ----------------
// 256 threads = 4 waves; wave owns 8 rows; lane owns feature pair f = 2*lane, 2*lane+1.
__global__ __launch_bounds__(256) void k_enc_head(const float* __restrict__ x, const float* __restrict__ den_in,
    const float* __restrict__ w1t, const float* __restrict__ b1v, const float* __restrict__ g1, const float* __restrict__ bb1,
    const float* __restrict__ w2t, const float* __restrict__ b2v, const float* __restrict__ g2, const float* __restrict__ bb2,
    const float* __restrict__ hw1t, const float* __restrict__ hb1, const float* __restrict__ hg, const float* __restrict__ hbb,
    const float* __restrict__ hw2, const float* __restrict__ hb2,
    float* __restrict__ spatial, float* __restrict__ pt_out){
  __shared__ __align__(16) float xbuf[32][68];
  __shared__ __align__(16) float hbuf[32][132];
  const int t = threadIdx.x, lane = t & 63, wid = t >> 6;
  const int row0 = blockIdx.x * 32;
  const int rbase = wid * 8;
  const int f0 = lane * 2;

  // stage 32 x-rows into LDS (coalesced)
  {
    const float4* xs = (const float4*)(x + (size_t)row0 * cI);
    #pragma unroll
    for (int i = 0; i < 2; ++i){
      int idx = t + i * 256;
      float4 v = xs[idx];
      *(float4*)&xbuf[idx >> 4][(idx & 15) * 4] = v;
    }
  }
  // den into slot 128 of each row (padded head input), 129..131 = 0
  if (lane < 8){
    float dn = den_in[row0 + rbase + lane];
    float* hd = &hbuf[rbase + lane][128];
    hd[0] = dn; hd[1] = 0.f; hd[2] = 0.f; hd[3] = 0.f;
  }
  __syncthreads();

  float2 b1p  = *(const float2*)(b1v + f0);
  float2 g1p  = *(const float2*)(g1  + f0);
  float2 bb1p = *(const float2*)(bb1 + f0);
  float2 b2p  = *(const float2*)(b2v + f0);
  float2 g2p  = *(const float2*)(g2  + f0);
  float2 bb2p = *(const float2*)(bb2 + f0);
  float2 hb1p = *(const float2*)(hb1 + f0);
  float2 hgp  = *(const float2*)(hg  + f0);
  float2 hbbp = *(const float2*)(hbb + f0);
  float2 hw2p = *(const float2*)(hw2 + f0);

  float accA[8], accB[8];

  // ---- layer 1: x(64) ----
  #pragma unroll
  for (int r = 0; r < 8; ++r){ accA[r] = b1p.x; accB[r] = b1p.y; }
  #pragma unroll 2
  for (int dc = 0; dc < 16; ++dc){
    float4 wA = *(const float4*)(w1t + ((size_t)dc * cH + f0) * 4);
    float4 wB = *(const float4*)(w1t + ((size_t)dc * cH + f0 + 1) * 4);
    #pragma unroll
    for (int r = 0; r < 8; ++r){
      float4 xv = *(const float4*)&xbuf[rbase + r][dc * 4];
      accA[r] += wA.x*xv.x + wA.y*xv.y + wA.z*xv.z + wA.w*xv.w;
      accB[r] += wB.x*xv.x + wB.y*xv.y + wB.z*xv.z + wB.w*xv.w;
    }
  }
  #pragma unroll
  for (int r = 0; r < 8; ++r){
    float sm = wred(accA[r] + accB[r]);
    float s2 = wred(accA[r]*accA[r] + accB[r]*accB[r]);
    float mean = sm * (1.f/128.f);
    float rstd = rsqrtf(s2 * (1.f/128.f) - mean*mean + 1e-5f);
    float hA = gelu_f((accA[r]-mean)*rstd*g1p.x + bb1p.x);
    float hB = gelu_f((accB[r]-mean)*rstd*g1p.y + bb1p.y);
    float2 hv = { hA, hB };
    *(float2*)&hbuf[rbase + r][f0] = hv;
  }
  __syncthreads();

  // ---- layer 2: h(128) ----
  #pragma unroll
  for (int r = 0; r < 8; ++r){ accA[r] = b2p.x; accB[r] = b2p.y; }
  #pragma unroll 2
  for (int dc = 0; dc < 32; ++dc){
    float4 wA = *(const float4*)(w2t + ((size_t)dc * cH + f0) * 4);
    float4 wB = *(const float4*)(w2t + ((size_t)dc * cH + f0 + 1) * 4);
    #pragma unroll
    for (int r = 0; r < 8; ++r){
      float4 hv = *(const float4*)&hbuf[rbase + r][dc * 4];
      accA[r] += wA.x*hv.x + wA.y*hv.y + wA.z*hv.z + wA.w*hv.w;
      accB[r] += wB.x*hv.x + wB.y*hv.y + wB.z*hv.z + wB.w*hv.w;
    }
  }
  #pragma unroll
  for (int r = 0; r < 8; ++r){
    float sm = wred(accA[r] + accB[r]);
    float s2 = wred(accA[r]*accA[r] + accB[r]*accB[r]);
    float mean = sm * (1.f/128.f);
    float rstd = rsqrtf(s2 * (1.f/128.f) - mean*mean + 1e-5f);
    float sA = (accA[r]-mean)*rstd*g2p.x + bb2p.x;
    float sB = (accB[r]-mean)*rstd*g2p.y + bb2p.y;
    float2 sv = { sA, sB };
    *(float2*)(spatial + (size_t)(row0 + rbase + r) * cH + f0) = sv;
    *(float2*)&hbuf[rbase + r][f0] = sv;     // all reads of hbuf done above (lockstep wave)
  }
  __syncthreads();

  // ---- head layer 1: [spatial(128), den] via 132-dim padded input ----
  #pragma unroll
  for (int r = 0; r < 8; ++r){ accA[r] = hb1p.x; accB[r] = hb1p.y; }
  #pragma unroll 2
  for (int dc = 0; dc < 33; ++dc){
    float4 wA = *(const float4*)(hw1t + ((size_t)dc * cH + f0) * 4);
    float4 wB = *(const float4*)(hw1t + ((size_t)dc * cH + f0 + 1) * 4);
    #pragma unroll
    for (int r = 0; r < 8; ++r){
      float4 hv = *(const float4*)&hbuf[rbase + r][dc * 4];
      accA[r] += wA.x*hv.x + wA.y*hv.y + wA.z*hv.z + wA.w*hv.w;
      accB[r] += wB.x*hv.x + wB.y*hv.y + wB.z*hv.z + wB.w*hv.w;
    }
  }
  #pragma unroll
  for (int r = 0; r < 8; ++r){
    float sm = wred(accA[r] + accB[r]);
    float s2 = wred(accA[r]*accA[r] + accB[r]*accB[r]);
    float mean = sm * (1.f/128.f);
    float rstd = rsqrtf(s2 * (1.f/128.f) - mean*mean + 1e-5f);
    float e0 = gelu_f((accA[r]-mean)*rstd*hgp.x + hbbp.x);
    float e1 = gelu_f((accB[r]-mean)*rstd*hgp.y + hbbp.y);
    float part = wred(e0*hw2p.x + e1*hw2p.y);
    if (lane == r){
      float ps = part + hb2[0];
      float spl = fmaxf(ps, 0.f) + log1pf(expf(-fabsf(ps)));
      float dn = hbuf[rbase + r][128];
      pt_out[row0 + rbase + r] = 5.f - 1.5f*dn + 0.5f*spl;
    }
  }
}

// ---------------- attention: 4 threads/row partial dots, softmax over 24 ----------------
__global__ __launch_bounds__(256) void k_attn(const float* __restrict__ spatial, const float* __restrict__ pt_in,
    const float* __restrict__ den_in, const float* __restrict__ objp, int ob_stride,
    const float* __restrict__ nsqp, int nq_stride,
    const float* __restrict__ lt, const float* __restrict__ bh, const float* __restrict__ hs,
    float* __restrict__ attn_out){
  int t = threadIdx.x;
  int sub = t & 3, rl = t >> 2;
  int id = blockIdx.x * 64 + rl;
  int b = id >> 11, n = id & 2047;

  float4 sv[8];
  const float4* sp4 = (const float4*)(spatial + (size_t)id * cH + sub * 32);
  #pragma unroll
  for (int i = 0; i < 8; ++i) sv[i] = sp4[i];
  float spn2 = 0.f;
  #pragma unroll
  for (int i = 0; i < 8; ++i) spn2 += sv[i].x*sv[i].x + sv[i].y*sv[i].y + sv[i].z*sv[i].z + sv[i].w*sv[i].w;

  const float* ob = objp + (size_t)b * ob_stride;
  float acc[8];
  #pragma unroll
  for (int o = 0; o < 8; ++o){
    const float4* orow = (const float4*)(ob + (size_t)o * cH + sub * 32);
    float a0=0,a1=0,a2=0,a3=0;
    #pragma unroll
    for (int i = 0; i < 8; ++i){ float4 w4 = orow[i];
      a0 += w4.x*sv[i].x; a1 += w4.y*sv[i].y; a2 += w4.z*sv[i].z; a3 += w4.w*sv[i].w; }
    acc[o] = (a0+a1)+(a2+a3);
  }
  spn2 += __shfl_xor(spn2, 1); spn2 += __shfl_xor(spn2, 2);
  #pragma unroll
  for (int o = 0; o < 8; ++o){ acc[o] += __shfl_xor(acc[o], 1); acc[o] += __shfl_xor(acc[o], 2); }

  if (sub != 0) return;

  const float* nq = nsqp + (size_t)b * nq_stride;
  float nsqv_[8];
  #pragma unroll
  for (int o = 0; o < 8; ++o) nsqv_[o] = nq[o];
  float pt = pt_in[id], den = den_in[id];
  float hsv = hs[0];
  float lts[3] = { lt[0], lt[1], lt[2] };
  float bhs[3] = { bh[0], bh[1], bh[2] };

  float logits[24];
  #pragma unroll
  for (int k = 0; k < 24; ++k){
    const int o = k / 3, l = k % 3;
    float dtv = pt - lts[l];
    float dr2 = fmaxf(spn2 + nsqv_[o] - 2.f * acc[o], 0.f);
    float ls  = dtv*dtv - dr2;
    float adL = sqrtf(fabsf(ls) + 1e-6f);
    float r   = sqrtf(dr2);
    float adt = fabsf(dtv);
    float hz  = fminf(fmaxf(bhs[l] + hsv * (den - 0.5f), 0.1f), 1.0f);
    float cone = hz - r / (adt + 1e-6f) - 10.f * fmaxf(-dtv, 0.f) - 5.f * fmaxf(r - adt, 0.f);
    logits[k] = (-adL + 0.5f * tanhf(cone)) * 10.f;
  }
  float mx = -3e38f;
  #pragma unroll
  for (int k = 0; k < 24; ++k) mx = fmaxf(mx, logits[k]);
  float es[24]; float ssum = 0.f;
  #pragma unroll
  for (int k = 0; k < 24; ++k){ es[k] = expf(logits[k] - mx); ssum += es[k]; }
  float inv = 1.f / ssum;
  float* ao = attn_out + (size_t)b * cK * cN + n;
  #pragma unroll
  for (int k = 0; k < 24; ++k) ao[(size_t)k * cN] = es[k] * inv;
}

// ---------------- upd[b,k,h] += sum_n attn*spatial ; S[b,k] += sum_n attn ----------------
__global__ __launch_bounds__(256) void k_upd(const float* __restrict__ spatial, const float* __restrict__ attn,
                                             float* __restrict__ upd_raw, float* __restrict__ Ssum){
  __shared__ float abuf[24][64];
  int blk = blockIdx.x;
  int b = blk >> 5, chunk = blk & 31;
  int n0 = chunk * 64;
  int t = threadIdx.x;
  const float* ab = attn + (size_t)b * cK * cN + n0;
  #pragma unroll
  for (int i = 0; i < 6; ++i){
    int idx = t + i * 256;
    abuf[idx >> 6][idx & 63] = ab[(size_t)(idx >> 6) * cN + (idx & 63)];
  }
  __syncthreads();
  int h = t & 127, g = t >> 7;
  float acc[12];
  #pragma unroll
  for (int kk = 0; kk < 12; ++kk) acc[kk] = 0.f;
  const float* sp = spatial + ((size_t)b * cN + n0) * cH + h;
  for (int ni = 0; ni < 64; ++ni){
    float spv = sp[(size_t)ni * cH];
    #pragma unroll
    for (int kk = 0; kk < 12; ++kk) acc[kk] += abuf[g*12+kk][ni] * spv;
  }
  #pragma unroll
  for (int kk = 0; kk < 12; ++kk)
    atomicAdd(&upd_raw[((size_t)b * cK + g*12+kk) * cH + h], acc[kk]);
  if (t < 24){
    float s = 0.f;
    #pragma unroll
    for (int j = 0; j < 64; ++j) s += abuf[t][j];
    atomicAdd(&Ssum[b * cK + t], s);
  }
}

// ---------------- GRU + LN + MLP residual ----------------
__global__ __launch_bounds__(128) void k_gru(const float* __restrict__ upd_raw, const float* __restrict__ Ssum,
    const float* __restrict__ ghs, const float* __restrict__ objsp,
    const float* __restrict__ w_ih, const float* __restrict__ b_ih,
    const float* __restrict__ mw1, const float* __restrict__ mb1,
    const float* __restrict__ mw2, const float* __restrict__ mb2,
    const float* __restrict__ ng_, const float* __restrict__ nb_,
    const float* __restrict__ lt,
    float* __restrict__ newobj, float* __restrict__ nsq,
    float* __restrict__ slots_out, int writeSlots){
  __shared__ float ubuf[cH], lbuf[cH], gbuf[cH], red[8];
  int bo = blockIdx.x; int b = bo >> 3, o = bo & 7;
  int t = threadIdx.x;
  int lane = t & 63, wid = t >> 6;

  float u = 0.f;
  #pragma unroll
  for (int l = 0; l < 3; ++l){
    int k = o * 3 + l;
    float s = Ssum[b * cK + k] + 1e-8f;
    u += upd_raw[((size_t)b * cK + k) * cH + t] / s;
  }
  ubuf[t] = u;
  __syncthreads();

  float gi[3];
  #pragma unroll
  for (int j3 = 0; j3 < 3; ++j3){
    const float* wr = w_ih + ((size_t)j3 * cH + t) * cH;
    float a0=0,a1=0,a2=0,a3=0;
    #pragma unroll
    for (int d = 0; d < cH; d += 4){
      a0 += wr[d]*ubuf[d]; a1 += wr[d+1]*ubuf[d+1]; a2 += wr[d+2]*ubuf[d+2]; a3 += wr[d+3]*ubuf[d+3];
    }
    gi[j3] = (a0+a1)+(a2+a3) + b_ih[j3 * cH + t];
  }
  const float* gh = ghs + (size_t)o * 3 * cH;
  float ghr = gh[t], ghz = gh[cH + t], ghn = gh[2 * cH + t];
  float oldv = objsp[(size_t)o * cH + t];
  float rg = 1.f / (1.f + expf(-(gi[0] + ghr)));
  float zg = 1.f / (1.f + expf(-(gi[1] + ghz)));
  float ngv = tanhf(gi[2] + rg * ghn);
  float nv = (1.f - zg) * ngv + zg * oldv;

  float s1 = nv, s2 = nv * nv;
  #pragma unroll
  for (int m = 1; m < 64; m <<= 1){ s1 += __shfl_xor(s1, m); s2 += __shfl_xor(s2, m); }
  if (lane == 0){ red[wid] = s1; red[4 + wid] = s2; }
  __syncthreads();
  float mean = (red[0] + red[1]) * (1.f/128.f);
  float var  = (red[4] + red[5]) * (1.f/128.f) - mean * mean;
  float ln = (nv - mean) * rsqrtf(var + 1e-5f) * ng_[t] + nb_[t];
  lbuf[t] = ln;
  __syncthreads();

  const float* w1r = mw1 + (size_t)t * cH;
  {
    float a0=0,a1=0,a2=0,a3=0;
    #pragma unroll
    for (int d = 0; d < cH; d += 4){
      a0 += w1r[d]*lbuf[d]; a1 += w1r[d+1]*lbuf[d+1]; a2 += w1r[d+2]*lbuf[d+2]; a3 += w1r[d+3]*lbuf[d+3];
    }
    gbuf[t] = gelu_f((a0+a1)+(a2+a3) + mb1[t]);
  }
  __syncthreads();
  const float* w2r = mw2 + (size_t)t * cH;
  float m2v;
  {
    float a0=0,a1=0,a2=0,a3=0;
    #pragma unroll
    for (int d = 0; d < cH; d += 4){
      a0 += w2r[d]*gbuf[d]; a1 += w2r[d+1]*gbuf[d+1]; a2 += w2r[d+2]*gbuf[d+2]; a3 += w2r[d+3]*gbuf[d+3];
    }
    m2v = (a0+a1)+(a2+a3) + mb2[t];
  }
  float outv = nv + 0.2f * m2v;
  newobj[((size_t)b * cO + o) * cH + t] = outv;

  float qv = outv * outv;
  #pragma unroll
  for (int m = 1; m < 64; m <<= 1) qv += __shfl_xor(qv, m);
  __syncthreads();
  if (lane == 0) red[wid] = qv;
  __syncthreads();
  if (t == 0) nsq[b * cO + o] = red[0] + red[1];

  if (writeSlots){
    #pragma unroll
    for (int l = 0; l < 3; ++l){
      size_t base = ((size_t)b * cK + o * 3 + l) * 129;
      slots_out[base + 1 + t] = outv;
      if (t == 0) slots_out[base] = lt[l];
    }
  }
}

extern "C" void kernel_launch(void* const* d_in, const int* in_sizes, int n_in,
                              void* d_out, int out_size, void* d_ws, size_t ws_size,
                              hipStream_t stream){
  const float* x       = (const float*)d_in[0];
  const float* enc_w1  = (const float*)d_in[1];
  const float* enc_b1  = (const float*)d_in[2];
  const float* enc_g1  = (const float*)d_in[3];
  const float* enc_bb1 = (const float*)d_in[4];
  const float* enc_w2  = (const float*)d_in[5];
  const float* enc_b2  = (const float*)d_in[6];
  const float* enc_g2  = (const float*)d_in[7];
  const float* enc_bb2 = (const float*)d_in[8];
  const float* sp_w1   = (const float*)d_in[9];
  const float* sp_b1   = (const float*)d_in[10];
  const float* sp_g    = (const float*)d_in[11];
  const float* sp_bb   = (const float*)d_in[12];
  const float* sp_w2   = (const float*)d_in[13];
  const float* sp_b2   = (const float*)d_in[14];
  const float* objsp   = (const float*)d_in[15];
  const float* hscale  = (const float*)d_in[16];
  const float* ltimes  = (const float*)d_in[17];
  const float* bhor    = (const float*)d_in[18];
  const float* gw_ih   = (const float*)d_in[19];
  const float* gw_hh   = (const float*)d_in[20];
  const float* gb_ih   = (const float*)d_in[21];
  const float* gb_hh   = (const float*)d_in[22];
  const float* mw1     = (const float*)d_in[23];
  const float* mb1     = (const float*)d_in[24];
  const float* mw2     = (const float*)d_in[25];
  const float* mb2     = (const float*)d_in[26];
  const float* normg   = (const float*)d_in[27];
  const float* normb   = (const float*)d_in[28];
  (void)in_sizes; (void)n_in; (void)out_size; (void)ws_size;

  float* out = (float*)d_out;
  float* ws  = (float*)d_ws;

  float* spatial = ws + WS_SPATIAL;
  float* sq      = ws + WS_SQ;
  float* ghs     = ws + WS_GHS;
  float* nsq0    = ws + WS_NSQ0;
  float* newobj  = ws + WS_NEWOBJ;
  float* nsqv    = ws + WS_NSQ;
  float* w1t     = ws + WS_W1T;
  float* w2t     = ws + WS_W2T;
  float* hw1t    = ws + WS_HW1T;
  float* updr3   = ws + WS_UPD3;
  float* Ss3     = ws + WS_S3;

  hipMemsetAsync((void*)updr3, 0, (size_t)(3 * cB * cK * cH + 3 * cB * cK) * sizeof(float), stream);

  k_sq<<<dim3(ROWS / 256), dim3(256), 0, stream>>>(x, sq);
  k_prep<<<dim3(175), dim3(256), 0, stream>>>(objsp, gw_hh, gb_hh, enc_w1, enc_w2, sp_w1,
                                              ghs, nsq0, w1t, w2t, hw1t);
  k_pairwise<<<dim3(cB * (cN / 16)), dim3(256), 0, stream>>>(x, sq, out + OUT_DEN);
  k_enc_head<<<dim3(ROWS / 32), dim3(256), 0, stream>>>(x, out + OUT_DEN,
      w1t, enc_b1, enc_g1, enc_bb1, w2t, enc_b2, enc_g2, enc_bb2,
      hw1t, sp_b1, sp_g, sp_bb, sp_w2, sp_b2,
      spatial, out + OUT_PT);

  for (int it = 0; it < 3; ++it){
    float* updr = updr3 + (size_t)it * cB * cK * cH;
    float* Ss   = Ss3 + (size_t)it * cB * cK;
    const float* objp = (it == 0) ? objsp : newobj;
    int obst = (it == 0) ? 0 : cO * cH;
    const float* nqp = (it == 0) ? nsq0 : nsqv;
    int nqst = (it == 0) ? 0 : cO;
    k_attn<<<dim3(ROWS / 64), dim3(256), 0, stream>>>(spatial, out + OUT_PT, out + OUT_DEN,
                                                      objp, obst, nqp, nqst,
                                                      ltimes, bhor, hscale, out + OUT_ATTN);
    k_upd<<<dim3(cB * 32), dim3(256), 0, stream>>>(spatial, out + OUT_ATTN, updr, Ss);
    k_gru<<<dim3(cB * cO), dim3(128), 0, stream>>>(updr, Ss, ghs, objsp, gw_ih, gb_ih,
                                                   mw1, mb1, mw2, mb2, normg, normb, ltimes,
                                                   newobj, nsqv, out + OUT_SLOTS, (it == 2) ? 1 : 0);
  }
}

// Round 6
// 339.851 us; speedup vs baseline: 3.1702x; 1.1341x over previous
//
#include <hip/hip_runtime.h>
#include <math.h>

// ---- problem dims ----
constexpr int cB = 8, cN = 2048, cI = 64, cH = 128, cO = 8, cK = 24;
constexpr int ROWS = cB * cN; // 16384

// ---- ws layout (floats) ----
constexpr size_t WS_SPATIAL = 0;                                  // 16384*128
constexpr size_t WS_SQ      = WS_SPATIAL + (size_t)ROWS * cH;     // 16384
constexpr size_t WS_GHS     = WS_SQ + ROWS;                       // 8*384
constexpr size_t WS_NSQ0    = WS_GHS + (size_t)cO * 3 * cH;       // 8
constexpr size_t WS_NEWOBJ  = WS_NSQ0 + cO;                       // 8*8*128
constexpr size_t WS_NSQ     = WS_NEWOBJ + (size_t)cB * cO * cH;   // 64
constexpr size_t WS_W1T     = WS_NSQ + (size_t)cB * cO;           // 16*128*4  = 8192
constexpr size_t WS_W2T     = WS_W1T + 8192;                      // 32*128*4  = 16384
constexpr size_t WS_HW1T    = WS_W2T + 16384;                     // 33*128*4  = 16896
constexpr size_t WS_UPD3    = WS_HW1T + 16896;                    // 3*8*24*128
constexpr size_t WS_S3      = WS_UPD3 + (size_t)3 * cB * cK * cH; // 3*8*24
constexpr size_t WS_XBF     = WS_S3 + (size_t)3 * cB * cK;        // 16384*64 bf16 = 524288 floats

// ---- d_out layout (floats), return order: slots, attn, pred_time, density ----
constexpr size_t OUT_SLOTS = 0;                                   // 8*24*129
constexpr size_t OUT_ATTN  = (size_t)cB * cK * 129;
constexpr size_t OUT_PT    = OUT_ATTN + (size_t)cB * cK * cN;
constexpr size_t OUT_DEN   = OUT_PT + (size_t)cB * cN;

typedef __attribute__((ext_vector_type(8))) short bf16x8;
typedef __attribute__((ext_vector_type(4))) float f32x4;

__device__ __forceinline__ float gelu_f(float v){
  return 0.5f * v * (1.f + erff(v * 0.70710678118654752440f));
}
__device__ __forceinline__ short f2bf(float f){
  unsigned u = __float_as_uint(f);
  u += 0x7fffu + ((u >> 16) & 1u);   // RNE
  return (short)(u >> 16);
}
__device__ __forceinline__ bf16x8 pack8(float4 a, float4 b){
  bf16x8 r;
  r[0]=f2bf(a.x); r[1]=f2bf(a.y); r[2]=f2bf(a.z); r[3]=f2bf(a.w);
  r[4]=f2bf(b.x); r[5]=f2bf(b.y); r[6]=f2bf(b.z); r[7]=f2bf(b.w);
  return r;
}
__device__ __forceinline__ float wred(float a){   // full-wave (64) butterfly sum
  a += __shfl_xor(a, 1); a += __shfl_xor(a, 2); a += __shfl_xor(a, 4);
  a += __shfl_xor(a, 8); a += __shfl_xor(a, 16); a += __shfl_xor(a, 32);
  return a;
}

// ---------------- x -> bf16 copy (RNE) + sq[b,n] = ||x||^2, fused & coalesced ----------------
// block = 256 threads = 32 rows (8 threads/row, 8 elems/thread)
__global__ __launch_bounds__(256) void k_cvt_sq(const float* __restrict__ x, short* __restrict__ xbf,
                                                float* __restrict__ sq){
  int t = threadIdx.x;
  size_t base = (size_t)blockIdx.x * 2048;   // floats
  int r = t >> 3, e0 = (t & 7) * 8;
  const float4* xp = (const float4*)(x + base + (size_t)r * cI + e0);
  float4 v0 = xp[0], v1 = xp[1];
  *(bf16x8*)(xbf + base + (size_t)r * cI + e0) = pack8(v0, v1);
  float s = v0.x*v0.x + v0.y*v0.y + v0.z*v0.z + v0.w*v0.w
          + v1.x*v1.x + v1.y*v1.y + v1.z*v1.z + v1.w*v1.w;
  s += __shfl_xor(s, 1); s += __shfl_xor(s, 2); s += __shfl_xor(s, 4);
  if ((t & 7) == 0) sq[blockIdx.x * 32 + r] = s;
}

// ---------------- prep: ghs, ||obj||^2, transposed d-chunked weight copies ----------------
__global__ __launch_bounds__(256) void k_prep(const float* __restrict__ objsp, const float* __restrict__ w_hh,
                                              const float* __restrict__ b_hh,
                                              const float* __restrict__ ew1, const float* __restrict__ ew2,
                                              const float* __restrict__ spw1,
                                              float* __restrict__ ghs, float* __restrict__ nsq0,
                                              float* __restrict__ w1t, float* __restrict__ w2t,
                                              float* __restrict__ hw1t){
  int id = blockIdx.x * 256 + threadIdx.x;
  if (id < cO * 3 * cH){
    int o = id / (3 * cH), j = id % (3 * cH);
    const float* wr = w_hh + (size_t)j * cH;
    const float* ob = objsp + (size_t)o * cH;
    float a0=0,a1=0,a2=0,a3=0;
    #pragma unroll
    for (int h = 0; h < cH; h += 4){
      a0 += wr[h]*ob[h]; a1 += wr[h+1]*ob[h+1]; a2 += wr[h+2]*ob[h+2]; a3 += wr[h+3]*ob[h+3];
    }
    ghs[id] = (a0+a1)+(a2+a3) + b_hh[j];
  } else if (id < cO * 3 * cH + cO){
    int o = id - cO * 3 * cH;
    const float* ob = objsp + (size_t)o * cH;
    float s = 0.f;
    for (int h = 0; h < cH; ++h) s += ob[h]*ob[h];
    nsq0[o] = s;
  } else {
    int idx = id - (cO * 3 * cH + cO);
    if (idx < 8192){                       // w1t: 16 dc
      int dc = idx >> 9, rem = idx & 511, f = rem >> 2, j = rem & 3;
      w1t[idx] = ew1[f * cI + dc * 4 + j];
    } else if (idx < 24576){               // w2t: 32 dc
      int k2 = idx - 8192;
      int dc = k2 >> 9, rem = k2 & 511, f = rem >> 2, j = rem & 3;
      w2t[k2] = ew2[f * cH + dc * 4 + j];
    } else if (idx < 41472){               // hw1t: 33 dc (d=128 -> den weight; 129..131 zero)
      int k3 = idx - 24576;
      int dc = k3 >> 9, rem = k3 & 511, f = rem >> 2, j = rem & 3;
      int d = dc * 4 + j;
      hw1t[k3] = (d < 129) ? spw1[f * 129 + d] : 0.f;
    }
  }
}

// ---------------- pairwise distances (pre-converted bf16) + fused per-row top-6 -> density ----------------
__global__ __launch_bounds__(256) void k_pairwise(const short* __restrict__ xbf, const float* __restrict__ sq,
                                                  float* __restrict__ den_out){
  __shared__ float cand[4][16][101];
  int b  = blockIdx.x >> 7;
  int rt = blockIdx.x & 127;
  int r0 = rt * 16;
  int lane = threadIdx.x & 63, w = threadIdx.x >> 6;
  const short* xb = xbf + (size_t)b * cN * cI;

  int arow = r0 + (lane & 15);
  int koff = (lane >> 4) * 8;
  const bf16x8* ap = (const bf16x8*)(xb + (size_t)arow * cI + koff);
  bf16x8 a0 = ap[0];        // k = koff..koff+7
  bf16x8 a1 = ap[4];        // k = 32+koff..

  float sqr[4];
  int rg0 = r0 + ((lane >> 4) << 2);
  #pragma unroll
  for (int j = 0; j < 4; ++j) sqr[j] = sq[b * cN + rg0 + j];

  float t6[4][6];
  #pragma unroll
  for (int j = 0; j < 4; ++j){
    #pragma unroll
    for (int q = 0; q < 6; ++q) t6[j][q] = 3e38f;
  }

  int cbase = w * 512;
  #pragma unroll 2
  for (int ct = 0; ct < 32; ++ct){
    int col0 = cbase + ct * 16;
    int brow = col0 + (lane & 15);
    const bf16x8* bp = (const bf16x8*)(xb + (size_t)brow * cI + koff);
    bf16x8 b0 = bp[0];
    bf16x8 b1 = bp[4];
    f32x4 acc = {0.f, 0.f, 0.f, 0.f};
    acc = __builtin_amdgcn_mfma_f32_16x16x32_bf16(a0, b0, acc, 0, 0, 0);
    acc = __builtin_amdgcn_mfma_f32_16x16x32_bf16(a1, b1, acc, 0, 0, 0);
    float sqc = sq[b * cN + col0 + (lane & 15)];
    #pragma unroll
    for (int j = 0; j < 4; ++j){
      float d2 = sqr[j] + sqc - 2.f * acc[j];   // C layout: col=lane&15, row=(lane>>4)*4+j
      d2 = fmaxf(d2, 0.f);
      if (d2 < t6[j][5]){
        if (d2 < t6[j][4]){ t6[j][5]=t6[j][4];
          if (d2 < t6[j][3]){ t6[j][4]=t6[j][3];
            if (d2 < t6[j][2]){ t6[j][3]=t6[j][2];
              if (d2 < t6[j][1]){ t6[j][2]=t6[j][1];
                if (d2 < t6[j][0]){ t6[j][1]=t6[j][0]; t6[j][0]=d2; } else t6[j][1]=d2;
              } else t6[j][2]=d2;
            } else t6[j][3]=d2;
          } else t6[j][4]=d2;
        } else t6[j][5]=d2;
      }
    }
  }
  int rloc = (lane >> 4) << 2;
  #pragma unroll
  for (int j = 0; j < 4; ++j){
    #pragma unroll
    for (int q = 0; q < 6; ++q) cand[w][rloc + j][(lane & 15) * 6 + q] = t6[j][q];
  }
  __syncthreads();
  int tt = threadIdx.x;
  // stage 2: 64 threads, each reduces one (wave,row) strip of 96 -> 6
  if (tt < 64){
    int ww = tt >> 4, rr = tt & 15;
    const float* c = cand[ww][rr];
    float m0=3e38f,m1=3e38f,m2=3e38f,m3=3e38f,m4=3e38f,m5=3e38f;
    #pragma unroll
    for (int q = 0; q < 96; ++q){
      float v = c[q];
      if (v < m5){
        if (v<m4){ m5=m4; if (v<m3){ m4=m3; if (v<m2){ m3=m2; if (v<m1){ m2=m1; if (v<m0){ m1=m0; m0=v; } else m1=v; } else m2=v; } else m3=v; } else m4=v; } else m5=v;
      }
    }
    float* cw = cand[ww][rr];
    cw[0]=m0; cw[1]=m1; cw[2]=m2; cw[3]=m3; cw[4]=m4; cw[5]=m5;
  }
  __syncthreads();
  // stage 3: 16 threads merge 4x6 -> top-6, emit density
  if (tt < 16){
    float m0=3e38f,m1=3e38f,m2=3e38f,m3=3e38f,m4=3e38f,m5=3e38f;
    #pragma unroll
    for (int ww = 0; ww < 4; ++ww){
      const float* c = cand[ww][tt];
      #pragma unroll
      for (int q = 0; q < 6; ++q){
        float v = c[q];
        if (v < m5){
          if (v<m4){ m5=m4; if (v<m3){ m4=m3; if (v<m2){ m3=m2; if (v<m1){ m2=m1; if (v<m0){ m1=m0; m0=v; } else m1=v; } else m2=v; } else m3=v; } else m4=v; } else m5=v;
        }
      }
    }
    float md = (sqrtf(m1)+sqrtf(m2)+sqrtf(m3)+sqrtf(m4)+sqrtf(m5)) * 0.2f;
    den_out[b * cN + r0 + tt] = tanhf(md);
  }
}

// ---------------- fused encoder + spatial head (lane-contiguous weights) ----------------
// 256 threads = 4 waves; wave owns 8 rows; lane owns feature pair f = 2*lane, 2*lane+1.
__global__ __launch_bounds__(256) void k_enc_head(const float* __restrict__ x, const float* __restrict__ den_in,
    const float* __restrict__ w1t, const float* __restrict__ b1v, const float* __restrict__ g1, const float* __restrict__ bb1,
    const float* __restrict__ w2t, const float* __restrict__ b2v, const float* __restrict__ g2, const float* __restrict__ bb2,
    const float* __restrict__ hw1t, const float* __restrict__ hb1, const float* __restrict__ hg, const float* __restrict__ hbb,
    const float* __restrict__ hw2, const float* __restrict__ hb2,
    float* __restrict__ spatial, float* __restrict__ pt_out){
  __shared__ __align__(16) float xbuf[32][68];
  __shared__ __align__(16) float hbuf[32][132];
  const int t = threadIdx.x, lane = t & 63, wid = t >> 6;
  const int row0 = blockIdx.x * 32;
  const int rbase = wid * 8;
  const int f0 = lane * 2;

  {
    const float4* xs = (const float4*)(x + (size_t)row0 * cI);
    #pragma unroll
    for (int i = 0; i < 2; ++i){
      int idx = t + i * 256;
      float4 v = xs[idx];
      *(float4*)&xbuf[idx >> 4][(idx & 15) * 4] = v;
    }
  }
  if (lane < 8){
    float dn = den_in[row0 + rbase + lane];
    float* hd = &hbuf[rbase + lane][128];
    hd[0] = dn; hd[1] = 0.f; hd[2] = 0.f; hd[3] = 0.f;
  }
  __syncthreads();

  float2 b1p  = *(const float2*)(b1v + f0);
  float2 g1p  = *(const float2*)(g1  + f0);
  float2 bb1p = *(const float2*)(bb1 + f0);
  float2 b2p  = *(const float2*)(b2v + f0);
  float2 g2p  = *(const float2*)(g2  + f0);
  float2 bb2p = *(const float2*)(bb2 + f0);
  float2 hb1p = *(const float2*)(hb1 + f0);
  float2 hgp  = *(const float2*)(hg  + f0);
  float2 hbbp = *(const float2*)(hbb + f0);
  float2 hw2p = *(const float2*)(hw2 + f0);

  float accA[8], accB[8];

  // ---- layer 1: x(64) ----
  #pragma unroll
  for (int r = 0; r < 8; ++r){ accA[r] = b1p.x; accB[r] = b1p.y; }
  #pragma unroll 2
  for (int dc = 0; dc < 16; ++dc){
    float4 wA = *(const float4*)(w1t + ((size_t)dc * cH + f0) * 4);
    float4 wB = *(const float4*)(w1t + ((size_t)dc * cH + f0 + 1) * 4);
    #pragma unroll
    for (int r = 0; r < 8; ++r){
      float4 xv = *(const float4*)&xbuf[rbase + r][dc * 4];
      accA[r] += wA.x*xv.x + wA.y*xv.y + wA.z*xv.z + wA.w*xv.w;
      accB[r] += wB.x*xv.x + wB.y*xv.y + wB.z*xv.z + wB.w*xv.w;
    }
  }
  #pragma unroll
  for (int r = 0; r < 8; ++r){
    float sm = wred(accA[r] + accB[r]);
    float s2 = wred(accA[r]*accA[r] + accB[r]*accB[r]);
    float mean = sm * (1.f/128.f);
    float rstd = rsqrtf(s2 * (1.f/128.f) - mean*mean + 1e-5f);
    float hA = gelu_f((accA[r]-mean)*rstd*g1p.x + bb1p.x);
    float hB = gelu_f((accB[r]-mean)*rstd*g1p.y + bb1p.y);
    float2 hv = { hA, hB };
    *(float2*)&hbuf[rbase + r][f0] = hv;
  }
  __syncthreads();

  // ---- layer 2: h(128) ----
  #pragma unroll
  for (int r = 0; r < 8; ++r){ accA[r] = b2p.x; accB[r] = b2p.y; }
  #pragma unroll 2
  for (int dc = 0; dc < 32; ++dc){
    float4 wA = *(const float4*)(w2t + ((size_t)dc * cH + f0) * 4);
    float4 wB = *(const float4*)(w2t + ((size_t)dc * cH + f0 + 1) * 4);
    #pragma unroll
    for (int r = 0; r < 8; ++r){
      float4 hv = *(const float4*)&hbuf[rbase + r][dc * 4];
      accA[r] += wA.x*hv.x + wA.y*hv.y + wA.z*hv.z + wA.w*hv.w;
      accB[r] += wB.x*hv.x + wB.y*hv.y + wB.z*hv.z + wB.w*hv.w;
    }
  }
  #pragma unroll
  for (int r = 0; r < 8; ++r){
    float sm = wred(accA[r] + accB[r]);
    float s2 = wred(accA[r]*accA[r] + accB[r]*accB[r]);
    float mean = sm * (1.f/128.f);
    float rstd = rsqrtf(s2 * (1.f/128.f) - mean*mean + 1e-5f);
    float sA = (accA[r]-mean)*rstd*g2p.x + bb2p.x;
    float sB = (accB[r]-mean)*rstd*g2p.y + bb2p.y;
    float2 sv = { sA, sB };
    *(float2*)(spatial + (size_t)(row0 + rbase + r) * cH + f0) = sv;
    *(float2*)&hbuf[rbase + r][f0] = sv;
  }
  __syncthreads();

  // ---- head layer 1: [spatial(128), den] via 132-dim padded input ----
  #pragma unroll
  for (int r = 0; r < 8; ++r){ accA[r] = hb1p.x; accB[r] = hb1p.y; }
  #pragma unroll 2
  for (int dc = 0; dc < 33; ++dc){
    float4 wA = *(const float4*)(hw1t + ((size_t)dc * cH + f0) * 4);
    float4 wB = *(const float4*)(hw1t + ((size_t)dc * cH + f0 + 1) * 4);
    #pragma unroll
    for (int r = 0; r < 8; ++r){
      float4 hv = *(const float4*)&hbuf[rbase + r][dc * 4];
      accA[r] += wA.x*hv.x + wA.y*hv.y + wA.z*hv.z + wA.w*hv.w;
      accB[r] += wB.x*hv.x + wB.y*hv.y + wB.z*hv.z + wB.w*hv.w;
    }
  }
  #pragma unroll
  for (int r = 0; r < 8; ++r){
    float sm = wred(accA[r] + accB[r]);
    float s2 = wred(accA[r]*accA[r] + accB[r]*accB[r]);
    float mean = sm * (1.f/128.f);
    float rstd = rsqrtf(s2 * (1.f/128.f) - mean*mean + 1e-5f);
    float e0 = gelu_f((accA[r]-mean)*rstd*hgp.x + hbbp.x);
    float e1 = gelu_f((accB[r]-mean)*rstd*hgp.y + hbbp.y);
    float part = wred(e0*hw2p.x + e1*hw2p.y);
    if (lane == r){
      float ps = part + hb2[0];
      float spl = fmaxf(ps, 0.f) + log1pf(expf(-fabsf(ps)));
      float dn = hbuf[rbase + r][128];
      pt_out[row0 + rbase + r] = 5.f - 1.5f*dn + 0.5f*spl;
    }
  }
}

// ---------------- attention: 4 threads/row partial dots, softmax over 24 ----------------
__global__ __launch_bounds__(256) void k_attn(const float* __restrict__ spatial, const float* __restrict__ pt_in,
    const float* __restrict__ den_in, const float* __restrict__ objp, int ob_stride,
    const float* __restrict__ nsqp, int nq_stride,
    const float* __restrict__ lt, const float* __restrict__ bh, const float* __restrict__ hs,
    float* __restrict__ attn_out){
  int t = threadIdx.x;
  int sub = t & 3, rl = t >> 2;
  int id = blockIdx.x * 64 + rl;
  int b = id >> 11, n = id & 2047;

  float4 sv[8];
  const float4* sp4 = (const float4*)(spatial + (size_t)id * cH + sub * 32);
  #pragma unroll
  for (int i = 0; i < 8; ++i) sv[i] = sp4[i];
  float spn2 = 0.f;
  #pragma unroll
  for (int i = 0; i < 8; ++i) spn2 += sv[i].x*sv[i].x + sv[i].y*sv[i].y + sv[i].z*sv[i].z + sv[i].w*sv[i].w;

  const float* ob = objp + (size_t)b * ob_stride;
  float acc[8];
  #pragma unroll
  for (int o = 0; o < 8; ++o){
    const float4* orow = (const float4*)(ob + (size_t)o * cH + sub * 32);
    float a0=0,a1=0,a2=0,a3=0;
    #pragma unroll
    for (int i = 0; i < 8; ++i){ float4 w4 = orow[i];
      a0 += w4.x*sv[i].x; a1 += w4.y*sv[i].y; a2 += w4.z*sv[i].z; a3 += w4.w*sv[i].w; }
    acc[o] = (a0+a1)+(a2+a3);
  }
  spn2 += __shfl_xor(spn2, 1); spn2 += __shfl_xor(spn2, 2);
  #pragma unroll
  for (int o = 0; o < 8; ++o){ acc[o] += __shfl_xor(acc[o], 1); acc[o] += __shfl_xor(acc[o], 2); }

  if (sub != 0) return;

  const float* nq = nsqp + (size_t)b * nq_stride;
  float nsqv_[8];
  #pragma unroll
  for (int o = 0; o < 8; ++o) nsqv_[o] = nq[o];
  float pt = pt_in[id], den = den_in[id];
  float hsv = hs[0];
  float lts[3] = { lt[0], lt[1], lt[2] };
  float bhs[3] = { bh[0], bh[1], bh[2] };

  float logits[24];
  #pragma unroll
  for (int k = 0; k < 24; ++k){
    const int o = k / 3, l = k % 3;
    float dtv = pt - lts[l];
    float dr2 = fmaxf(spn2 + nsqv_[o] - 2.f * acc[o], 0.f);
    float ls  = dtv*dtv - dr2;
    float adL = sqrtf(fabsf(ls) + 1e-6f);
    float r   = sqrtf(dr2);
    float adt = fabsf(dtv);
    float hz  = fminf(fmaxf(bhs[l] + hsv * (den - 0.5f), 0.1f), 1.0f);
    float cone = hz - r / (adt + 1e-6f) - 10.f * fmaxf(-dtv, 0.f) - 5.f * fmaxf(r - adt, 0.f);
    logits[k] = (-adL + 0.5f * tanhf(cone)) * 10.f;
  }
  float mx = -3e38f;
  #pragma unroll
  for (int k = 0; k < 24; ++k) mx = fmaxf(mx, logits[k]);
  float es[24]; float ssum = 0.f;
  #pragma unroll
  for (int k = 0; k < 24; ++k){ es[k] = expf(logits[k] - mx); ssum += es[k]; }
  float inv = 1.f / ssum;
  float* ao = attn_out + (size_t)b * cK * cN + n;
  #pragma unroll
  for (int k = 0; k < 24; ++k) ao[(size_t)k * cN] = es[k] * inv;
}

// ---------------- upd[b,k,h] += sum_n attn*spatial ; S[b,k] += sum_n attn ----------------
__global__ __launch_bounds__(256) void k_upd(const float* __restrict__ spatial, const float* __restrict__ attn,
                                             float* __restrict__ upd_raw, float* __restrict__ Ssum){
  __shared__ float abuf[24][64];
  int blk = blockIdx.x;
  int b = blk >> 5, chunk = blk & 31;
  int n0 = chunk * 64;
  int t = threadIdx.x;
  const float* ab = attn + (size_t)b * cK * cN + n0;
  #pragma unroll
  for (int i = 0; i < 6; ++i){
    int idx = t + i * 256;
    abuf[idx >> 6][idx & 63] = ab[(size_t)(idx >> 6) * cN + (idx & 63)];
  }
  __syncthreads();
  int h = t & 127, g = t >> 7;
  float acc[12];
  #pragma unroll
  for (int kk = 0; kk < 12; ++kk) acc[kk] = 0.f;
  const float* sp = spatial + ((size_t)b * cN + n0) * cH + h;
  for (int ni = 0; ni < 64; ++ni){
    float spv = sp[(size_t)ni * cH];
    #pragma unroll
    for (int kk = 0; kk < 12; ++kk) acc[kk] += abuf[g*12+kk][ni] * spv;
  }
  #pragma unroll
  for (int kk = 0; kk < 12; ++kk)
    atomicAdd(&upd_raw[((size_t)b * cK + g*12+kk) * cH + h], acc[kk]);
  if (t < 24){
    float s = 0.f;
    #pragma unroll
    for (int j = 0; j < 64; ++j) s += abuf[t][j];
    atomicAdd(&Ssum[b * cK + t], s);
  }
}

// ---------------- GRU + LN + MLP residual ----------------
__global__ __launch_bounds__(128) void k_gru(const float* __restrict__ upd_raw, const float* __restrict__ Ssum,
    const float* __restrict__ ghs, const float* __restrict__ objsp,
    const float* __restrict__ w_ih, const float* __restrict__ b_ih,
    const float* __restrict__ mw1, const float* __restrict__ mb1,
    const float* __restrict__ mw2, const float* __restrict__ mb2,
    const float* __restrict__ ng_, const float* __restrict__ nb_,
    const float* __restrict__ lt,
    float* __restrict__ newobj, float* __restrict__ nsq,
    float* __restrict__ slots_out, int writeSlots){
  __shared__ float ubuf[cH], lbuf[cH], gbuf[cH], red[8];
  int bo = blockIdx.x; int b = bo >> 3, o = bo & 7;
  int t = threadIdx.x;
  int lane = t & 63, wid = t >> 6;

  float u = 0.f;
  #pragma unroll
  for (int l = 0; l < 3; ++l){
    int k = o * 3 + l;
    float s = Ssum[b * cK + k] + 1e-8f;
    u += upd_raw[((size_t)b * cK + k) * cH + t] / s;
  }
  ubuf[t] = u;
  __syncthreads();

  float gi[3];
  #pragma unroll
  for (int j3 = 0; j3 < 3; ++j3){
    const float* wr = w_ih + ((size_t)j3 * cH + t) * cH;
    float a0=0,a1=0,a2=0,a3=0;
    #pragma unroll
    for (int d = 0; d < cH; d += 4){
      a0 += wr[d]*ubuf[d]; a1 += wr[d+1]*ubuf[d+1]; a2 += wr[d+2]*ubuf[d+2]; a3 += wr[d+3]*ubuf[d+3];
    }
    gi[j3] = (a0+a1)+(a2+a3) + b_ih[j3 * cH + t];
  }
  const float* gh = ghs + (size_t)o * 3 * cH;
  float ghr = gh[t], ghz = gh[cH + t], ghn = gh[2 * cH + t];
  float oldv = objsp[(size_t)o * cH + t];
  float rg = 1.f / (1.f + expf(-(gi[0] + ghr)));
  float zg = 1.f / (1.f + expf(-(gi[1] + ghz)));
  float ngv = tanhf(gi[2] + rg * ghn);
  float nv = (1.f - zg) * ngv + zg * oldv;

  float s1 = nv, s2 = nv * nv;
  #pragma unroll
  for (int m = 1; m < 64; m <<= 1){ s1 += __shfl_xor(s1, m); s2 += __shfl_xor(s2, m); }
  if (lane == 0){ red[wid] = s1; red[4 + wid] = s2; }
  __syncthreads();
  float mean = (red[0] + red[1]) * (1.f/128.f);
  float var  = (red[4] + red[5]) * (1.f/128.f) - mean * mean;
  float ln = (nv - mean) * rsqrtf(var + 1e-5f) * ng_[t] + nb_[t];
  lbuf[t] = ln;
  __syncthreads();

  const float* w1r = mw1 + (size_t)t * cH;
  {
    float a0=0,a1=0,a2=0,a3=0;
    #pragma unroll
    for (int d = 0; d < cH; d += 4){
      a0 += w1r[d]*lbuf[d]; a1 += w1r[d+1]*lbuf[d+1]; a2 += w1r[d+2]*lbuf[d+2]; a3 += w1r[d+3]*lbuf[d+3];
    }
    gbuf[t] = gelu_f((a0+a1)+(a2+a3) + mb1[t]);
  }
  __syncthreads();
  const float* w2r = mw2 + (size_t)t * cH;
  float m2v;
  {
    float a0=0,a1=0,a2=0,a3=0;
    #pragma unroll
    for (int d = 0; d < cH; d += 4){
      a0 += w2r[d]*gbuf[d]; a1 += w2r[d+1]*gbuf[d+1]; a2 += w2r[d+2]*gbuf[d+2]; a3 += w2r[d+3]*gbuf[d+3];
    }
    m2v = (a0+a1)+(a2+a3) + mb2[t];
  }
  float outv = nv + 0.2f * m2v;
  newobj[((size_t)b * cO + o) * cH + t] = outv;

  float qv = outv * outv;
  #pragma unroll
  for (int m = 1; m < 64; m <<= 1) qv += __shfl_xor(qv, m);
  __syncthreads();
  if (lane == 0) red[wid] = qv;
  __syncthreads();
  if (t == 0) nsq[b * cO + o] = red[0] + red[1];

  if (writeSlots){
    #pragma unroll
    for (int l = 0; l < 3; ++l){
      size_t base = ((size_t)b * cK + o * 3 + l) * 129;
      slots_out[base + 1 + t] = outv;
      if (t == 0) slots_out[base] = lt[l];
    }
  }
}

extern "C" void kernel_launch(void* const* d_in, const int* in_sizes, int n_in,
                              void* d_out, int out_size, void* d_ws, size_t ws_size,
                              hipStream_t stream){
  const float* x       = (const float*)d_in[0];
  const float* enc_w1  = (const float*)d_in[1];
  const float* enc_b1  = (const float*)d_in[2];
  const float* enc_g1  = (const float*)d_in[3];
  const float* enc_bb1 = (const float*)d_in[4];
  const float* enc_w2  = (const float*)d_in[5];
  const float* enc_b2  = (const float*)d_in[6];
  const float* enc_g2  = (const float*)d_in[7];
  const float* enc_bb2 = (const float*)d_in[8];
  const float* sp_w1   = (const float*)d_in[9];
  const float* sp_b1   = (const float*)d_in[10];
  const float* sp_g    = (const float*)d_in[11];
  const float* sp_bb   = (const float*)d_in[12];
  const float* sp_w2   = (const float*)d_in[13];
  const float* sp_b2   = (const float*)d_in[14];
  const float* objsp   = (const float*)d_in[15];
  const float* hscale  = (const float*)d_in[16];
  const float* ltimes  = (const float*)d_in[17];
  const float* bhor    = (const float*)d_in[18];
  const float* gw_ih   = (const float*)d_in[19];
  const float* gw_hh   = (const float*)d_in[20];
  const float* gb_ih   = (const float*)d_in[21];
  const float* gb_hh   = (const float*)d_in[22];
  const float* mw1     = (const float*)d_in[23];
  const float* mb1     = (const float*)d_in[24];
  const float* mw2     = (const float*)d_in[25];
  const float* mb2     = (const float*)d_in[26];
  const float* normg   = (const float*)d_in[27];
  const float* normb   = (const float*)d_in[28];
  (void)in_sizes; (void)n_in; (void)out_size; (void)ws_size;

  float* out = (float*)d_out;
  float* ws  = (float*)d_ws;

  float* spatial = ws + WS_SPATIAL;
  float* sq      = ws + WS_SQ;
  float* ghs     = ws + WS_GHS;
  float* nsq0    = ws + WS_NSQ0;
  float* newobj  = ws + WS_NEWOBJ;
  float* nsqv    = ws + WS_NSQ;
  float* w1t     = ws + WS_W1T;
  float* w2t     = ws + WS_W2T;
  float* hw1t    = ws + WS_HW1T;
  float* updr3   = ws + WS_UPD3;
  float* Ss3     = ws + WS_S3;
  short* xbf     = (short*)(ws + WS_XBF);

  hipMemsetAsync((void*)updr3, 0, (size_t)(3 * cB * cK * cH + 3 * cB * cK) * sizeof(float), stream);

  k_cvt_sq<<<dim3(ROWS / 32), dim3(256), 0, stream>>>(x, xbf, sq);
  k_prep<<<dim3(175), dim3(256), 0, stream>>>(objsp, gw_hh, gb_hh, enc_w1, enc_w2, sp_w1,
                                              ghs, nsq0, w1t, w2t, hw1t);
  k_pairwise<<<dim3(cB * (cN / 16)), dim3(256), 0, stream>>>(xbf, sq, out + OUT_DEN);
  k_enc_head<<<dim3(ROWS / 32), dim3(256), 0, stream>>>(x, out + OUT_DEN,
      w1t, enc_b1, enc_g1, enc_bb1, w2t, enc_b2, enc_g2, enc_bb2,
      hw1t, sp_b1, sp_g, sp_bb, sp_w2, sp_b2,
      spatial, out + OUT_PT);

  for (int it = 0; it < 3; ++it){
    float* updr = updr3 + (size_t)it * cB * cK * cH;
    float* Ss   = Ss3 + (size_t)it * cB * cK;
    const float* objp = (it == 0) ? objsp : newobj;
    int obst = (it == 0) ? 0 : cO * cH;
    const float* nqp = (it == 0) ? nsq0 : nsqv;
    int nqst = (it == 0) ? 0 : cO;
    k_attn<<<dim3(ROWS / 64), dim3(256), 0, stream>>>(spatial, out + OUT_PT, out + OUT_DEN,
                                                      objp, obst, nqp, nqst,
                                                      ltimes, bhor, hscale, out + OUT_ATTN);
    k_upd<<<dim3(cB * 32), dim3(256), 0, stream>>>(spatial, out + OUT_ATTN, updr, Ss);
    k_gru<<<dim3(cB * cO), dim3(128), 0, stream>>>(updr, Ss, ghs, objsp, gw_ih, gb_ih,
                                                   mw1, mb1, mw2, mb2, normg, normb, ltimes,
                                                   newobj, nsqv, out + OUT_SLOTS, (it == 2) ? 1 : 0);
  }
}